// Round 1
// baseline (2693.036 us; speedup 1.0000x reference)
//
#include <hip/hip_runtime.h>
#include <stdint.h>
#include <math.h>

#define NV 32768      // N = B*T
#define DIM 256       // D
#define KCB 1024      // K
#define NSAMP 5       // S

// ---------------- threefry2x32 (20 rounds), JAX key = (0, 42) ----------------
__device__ __forceinline__ uint32_t rotl32(uint32_t v, int r) {
  return (v << r) | (v >> (32 - r));
}

__device__ __forceinline__ void threefry2x32(uint32_t c0, uint32_t c1,
                                             uint32_t& o0, uint32_t& o1) {
  const uint32_t k0 = 0u, k1 = 42u;
  const uint32_t k2 = k0 ^ k1 ^ 0x1BD11BDAu;
  uint32_t x0 = c0 + k0, x1 = c1 + k1;
  // group 1 (rot set 0)
  x0 += x1; x1 = rotl32(x1, 13); x1 ^= x0;
  x0 += x1; x1 = rotl32(x1, 15); x1 ^= x0;
  x0 += x1; x1 = rotl32(x1, 26); x1 ^= x0;
  x0 += x1; x1 = rotl32(x1,  6); x1 ^= x0;
  x0 += k1; x1 += k2 + 1u;
  // group 2 (rot set 1)
  x0 += x1; x1 = rotl32(x1, 17); x1 ^= x0;
  x0 += x1; x1 = rotl32(x1, 29); x1 ^= x0;
  x0 += x1; x1 = rotl32(x1, 16); x1 ^= x0;
  x0 += x1; x1 = rotl32(x1, 24); x1 ^= x0;
  x0 += k2; x1 += k0 + 2u;
  // group 3
  x0 += x1; x1 = rotl32(x1, 13); x1 ^= x0;
  x0 += x1; x1 = rotl32(x1, 15); x1 ^= x0;
  x0 += x1; x1 = rotl32(x1, 26); x1 ^= x0;
  x0 += x1; x1 = rotl32(x1,  6); x1 ^= x0;
  x0 += k0; x1 += k1 + 3u;
  // group 4
  x0 += x1; x1 = rotl32(x1, 17); x1 ^= x0;
  x0 += x1; x1 = rotl32(x1, 29); x1 ^= x0;
  x0 += x1; x1 = rotl32(x1, 16); x1 ^= x0;
  x0 += x1; x1 = rotl32(x1, 24); x1 ^= x0;
  x0 += k1; x1 += k2 + 4u;
  // group 5
  x0 += x1; x1 = rotl32(x1, 13); x1 ^= x0;
  x0 += x1; x1 = rotl32(x1, 15); x1 ^= x0;
  x0 += x1; x1 = rotl32(x1, 26); x1 ^= x0;
  x0 += x1; x1 = rotl32(x1,  6); x1 ^= x0;
  x0 += k2; x1 += k0 + 5u;
  o0 = x0; o1 = x1;
}

// gumbel = -log(-log(u)) with JAX's exact f32 uniform bit pipeline; logs in f64
// then rounded to f32 (correctly rounded, matches glibc correctly-rounded logf).
__device__ __forceinline__ float gumbel_f32(uint32_t bits) {
  uint32_t m = bits >> 9;
  float u = (m == 0u) ? 1.17549435e-38f
                      : (__uint_as_float(m | 0x3f800000u) - 1.0f);
  float t = (float)(-log((double)u));
  float g = (float)(-log((double)t));
  return g;
}

// ------------------------------- kernels -------------------------------------

// wT[d*K + k] = w[k*D + d]
__global__ __launch_bounds__(256) void k_transpose(const float* __restrict__ w,
                                                   float* __restrict__ wT) {
  int id = blockIdx.x * 256 + threadIdx.x;   // < K*D
  int k = id >> 8, d = id & 255;
  wT[d * KCB + k] = w[id];
}

// sequential f32 sum of squares per row (mimic XLA:CPU minor-axis reduce)
__global__ __launch_bounds__(256) void k_rowsumsq(const float* __restrict__ a,
                                                  float* __restrict__ outp,
                                                  int rows) {
  int r = blockIdx.x * blockDim.x + threadIdx.x;
  if (r >= rows) return;
  const float* p = a + (size_t)r * DIM;
  float acc = 0.0f;
  for (int i = 0; i < DIM; ++i) {
    float pi = p[i];
    acc = __fadd_rn(acc, __fmul_rn(pi, pi));
  }
  outp[r] = acc;
}

// one block per row n: exact-f64 dots vs all K codes, then S gumbel-argmax samples
__global__ __launch_bounds__(256) void k_sample(const float* __restrict__ x,
                                                const float* __restrict__ wT,
                                                const float* __restrict__ wsum,
                                                const float* __restrict__ xsum,
                                                int* __restrict__ samples,
                                                int* __restrict__ cnt) {
  int n = blockIdx.x;
  int t = threadIdx.x;
  __shared__ float xrow[DIM];
  __shared__ float lrow[KCB];
  __shared__ float vred[256];
  __shared__ int   kred[256];

  xrow[t] = x[(size_t)n * DIM + t];
  __syncthreads();

  double acc0 = 0.0, acc1 = 0.0, acc2 = 0.0, acc3 = 0.0;
  for (int d = 0; d < DIM; ++d) {
    double xd = (double)xrow[d];
    const float* wp = wT + (size_t)d * KCB;
    acc0 += xd * (double)wp[t];
    acc1 += xd * (double)wp[t + 256];
    acc2 += xd * (double)wp[t + 512];
    acc3 += xd * (double)wp[t + 768];
  }
  float xs = xsum[n];
  // logits = -(f32(wsum_k + xsum_n) - f32(2*dot)) ; -(a-b) == (b-a) in IEEE
  lrow[t]       = __fsub_rn(__fmul_rn(2.0f, (float)acc0), __fadd_rn(wsum[t],       xs));
  lrow[t + 256] = __fsub_rn(__fmul_rn(2.0f, (float)acc1), __fadd_rn(wsum[t + 256], xs));
  lrow[t + 512] = __fsub_rn(__fmul_rn(2.0f, (float)acc2), __fadd_rn(wsum[t + 512], xs));
  lrow[t + 768] = __fsub_rn(__fmul_rn(2.0f, (float)acc3), __fadd_rn(wsum[t + 768], xs));
  __syncthreads();

  for (int s = 0; s < NSAMP; ++s) {
    uint32_t fbase = ((uint32_t)s * (uint32_t)NV + (uint32_t)n) * (uint32_t)KCB;
    float best = -INFINITY;
    int bk = 0;
    for (int j = 0; j < 4; ++j) {
      int k = t + j * 256;                 // ascending k within thread
      uint32_t o0, o1;
      threefry2x32(0u, fbase + (uint32_t)k, o0, o1);  // counter = (hi=0, lo=index)
      float g = gumbel_f32(o0 ^ o1);       // partitionable 32-bit fold
      float v = __fadd_rn(g, lrow[k]);
      if (v > best) { best = v; bk = k; }  // strict > => first max wins
    }
    vred[t] = best; kred[t] = bk;
    __syncthreads();
    for (int off = 128; off > 0; off >>= 1) {
      if (t < off) {
        float v2 = vred[t + off]; int k2 = kred[t + off];
        if (v2 > vred[t] || (v2 == vred[t] && k2 < kred[t])) {
          vred[t] = v2; kred[t] = k2;
        }
      }
      __syncthreads();
    }
    if (t == 0) {
      samples[s * NV + n] = kred[0];
      atomicAdd(&cnt[kred[0]], 1);
    }
    __syncthreads();
  }
}

// accumulate sum of x vectors per selected code (f64 atomics)
__global__ __launch_bounds__(256) void k_scatter(const float* __restrict__ x,
                                                 const int* __restrict__ samples,
                                                 double* __restrict__ sumx) {
  int n = blockIdx.x, t = threadIdx.x;
  double xv = (double)x[(size_t)n * DIM + t];
  for (int s = 0; s < NSAMP; ++s) {
    int k = samples[s * NV + n];
    __hip_atomic_fetch_add(&sumx[(size_t)k * DIM + t], xv,
                           __ATOMIC_RELAXED, __HIP_MEMORY_SCOPE_AGENT);
  }
}

// finalize counts (normalized), perplexity
__global__ __launch_bounds__(1024) void k_cfinal(const float* __restrict__ ema_count,
                                                 const int* __restrict__ cnt,
                                                 double* __restrict__ ncn64,
                                                 float* __restrict__ out_count,
                                                 float* __restrict__ out_perp) {
  __shared__ double red[1024];
  int k = threadIdx.x;
  double ec = (double)cnt[k] * 0.2;                       // column sum of encodings
  double nc0 = 0.999 * (double)ema_count[k] + 0.001 * ec;
  red[k] = nc0;
  __syncthreads();
  for (int off = 512; off > 0; off >>= 1) {
    if (k < off) red[k] += red[k + off];
    __syncthreads();
  }
  double ntot = red[0];
  __syncthreads();
  double ncn = (nc0 + 1e-5) / (ntot + (double)KCB * 1e-5) * ntot;
  ncn64[k] = ncn;
  out_count[k] = (float)ncn;

  // perplexity from avg_probs = colsum(encodings)/N
  double avg = ec / (double)NV;
  red[k] = avg * log(avg + 1e-10);
  __syncthreads();
  for (int off = 512; off > 0; off >>= 1) {
    if (k < off) red[k] += red[k + off];
    __syncthreads();
  }
  if (k == 0) out_perp[0] = (float)exp(-red[0]);
}

// new_weight, new_embedding
__global__ __launch_bounds__(256) void k_weight(const float* __restrict__ ema_w,
                                                const double* __restrict__ sumx,
                                                const double* __restrict__ ncn64,
                                                float* __restrict__ out_w,
                                                float* __restrict__ out_emb,
                                                float* __restrict__ emb32) {
  int k = blockIdx.x, d = threadIdx.x;
  size_t i = (size_t)k * DIM + d;
  double dw = 0.2 * sumx[i];
  double nw = 0.999 * (double)ema_w[i] + 0.001 * dw;
  float nw32 = (float)nw;
  float e = __fdiv_rn(nw32, (float)ncn64[k]);
  out_w[i] = nw32;
  out_emb[i] = e;
  emb32[i] = e;
}

// quantized_st + latent-loss partial sums
__global__ __launch_bounds__(256) void k_quant(const float* __restrict__ x,
                                               const int* __restrict__ samples,
                                               const float* __restrict__ emb32,
                                               float* __restrict__ out_q,
                                               double* __restrict__ lossacc) {
  int n = blockIdx.x, t = threadIdx.x;
  __shared__ int s5[NSAMP];
  __shared__ double wsum4[4];
  if (t < NSAMP) s5[t] = samples[t * NV + n];
  __syncthreads();
  float xv = x[(size_t)n * DIM + t];
  float acc = emb32[(size_t)s5[0] * DIM + t];
  for (int s = 1; s < NSAMP; ++s)
    acc = __fadd_rn(acc, emb32[(size_t)s5[s] * DIM + t]);
  float q = __fdiv_rn(acc, 5.0f);
  out_q[(size_t)n * DIM + t] = __fadd_rn(xv, __fsub_rn(q, xv));
  float df = __fsub_rn(xv, q);
  double v = (double)df * (double)df;
  for (int off = 32; off > 0; off >>= 1) v += __shfl_down(v, off);
  int wid = t >> 6, lane = t & 63;
  if (lane == 0) wsum4[wid] = v;
  __syncthreads();
  if (t == 0) {
    double b = wsum4[0] + wsum4[1] + wsum4[2] + wsum4[3];
    __hip_atomic_fetch_add(lossacc, b, __ATOMIC_RELAXED, __HIP_MEMORY_SCOPE_AGENT);
  }
}

__global__ void k_loss(const double* __restrict__ lossacc,
                       float* __restrict__ out_loss) {
  out_loss[0] = (float)(0.25 * (lossacc[0] / (double)(NV * DIM)));
}

// ------------------------------- launcher ------------------------------------
extern "C" void kernel_launch(void* const* d_in, const int* in_sizes, int n_in,
                              void* d_out, int out_size, void* d_ws, size_t ws_size,
                              hipStream_t stream) {
  const float* x     = (const float*)d_in[0];   // [64,512,256]
  const float* emb   = (const float*)d_in[1];   // [1024,256]
  const float* ema_c = (const float*)d_in[2];   // [1024]
  const float* ema_w = (const float*)d_in[3];   // [1024,256]

  float* out      = (float*)d_out;
  float* out_q    = out;                 // 8,388,608
  float* out_loss = out + 8388608;       // 1
  float* out_perp = out + 8388609;       // 1
  float* out_emb  = out + 8388610;       // 262,144
  float* out_cnt  = out + 8650754;       // 1,024
  float* out_w    = out + 8651778;       // 262,144  (end 8,913,922)

  char* ws = (char*)d_ws;
  float*  wT      = (float*)(ws + 0);         // 1,048,576 B
  float*  wsum    = (float*)(ws + 1048576);   // 4,096 B
  float*  xsum    = (float*)(ws + 1052672);   // 131,072 B
  int*    samples = (int*)  (ws + 1183744);   // 655,360 B
  int*    cnt     = (int*)  (ws + 1839104);   // 4,096 B   (zeroed)
  double* sumx    = (double*)(ws + 1843200);  // 2,097,152 B (zeroed)
  double* lossacc = (double*)(ws + 3940352);  // 8 B       (zeroed)
  double* ncn64   = (double*)(ws + 3940360);  // 8,192 B
  float*  emb32   = (float*)(ws + 3948552);   // 1,048,576 B -> total ~4.99 MB

  // zero the accumulators (cnt + sumx + lossacc are contiguous)
  hipMemsetAsync(ws + 1839104, 0, 4096 + 2097152 + 8, stream);

  k_transpose<<<KCB * DIM / 256, 256, 0, stream>>>(emb, wT);
  k_rowsumsq<<<KCB / 256, 256, 0, stream>>>(emb, wsum, KCB);
  k_rowsumsq<<<NV / 256, 256, 0, stream>>>(x, xsum, NV);
  k_sample<<<NV, 256, 0, stream>>>(x, wT, wsum, xsum, samples, cnt);
  k_scatter<<<NV, 256, 0, stream>>>(x, samples, sumx);
  k_cfinal<<<1, 1024, 0, stream>>>(ema_c, cnt, ncn64, out_cnt, out_perp);
  k_weight<<<KCB, 256, 0, stream>>>(ema_w, sumx, ncn64, out_w, out_emb, emb32);
  k_quant<<<NV, 256, 0, stream>>>(x, samples, emb32, out_q, lossacc);
  k_loss<<<1, 1, 0, stream>>>(lossacc, out_loss);
}

// Round 2
// 2527.292 us; speedup vs baseline: 1.0656x; 1.0656x over previous
//
#include <hip/hip_runtime.h>
#include <stdint.h>
#include <math.h>

#define NV 32768      // N = B*T
#define DIM 256       // D
#define KCB 1024      // K
#define NSAMP 5       // S

// ---------------- threefry2x32 (20 rounds), JAX key = (0, 42) ----------------
__device__ __forceinline__ uint32_t rotl32(uint32_t v, int r) {
  return (v << r) | (v >> (32 - r));
}

__device__ __forceinline__ void threefry2x32(uint32_t c0, uint32_t c1,
                                             uint32_t& o0, uint32_t& o1) {
  const uint32_t k0 = 0u, k1 = 42u;
  const uint32_t k2 = k0 ^ k1 ^ 0x1BD11BDAu;
  uint32_t x0 = c0 + k0, x1 = c1 + k1;
  x0 += x1; x1 = rotl32(x1, 13); x1 ^= x0;
  x0 += x1; x1 = rotl32(x1, 15); x1 ^= x0;
  x0 += x1; x1 = rotl32(x1, 26); x1 ^= x0;
  x0 += x1; x1 = rotl32(x1,  6); x1 ^= x0;
  x0 += k1; x1 += k2 + 1u;
  x0 += x1; x1 = rotl32(x1, 17); x1 ^= x0;
  x0 += x1; x1 = rotl32(x1, 29); x1 ^= x0;
  x0 += x1; x1 = rotl32(x1, 16); x1 ^= x0;
  x0 += x1; x1 = rotl32(x1, 24); x1 ^= x0;
  x0 += k2; x1 += k0 + 2u;
  x0 += x1; x1 = rotl32(x1, 13); x1 ^= x0;
  x0 += x1; x1 = rotl32(x1, 15); x1 ^= x0;
  x0 += x1; x1 = rotl32(x1, 26); x1 ^= x0;
  x0 += x1; x1 = rotl32(x1,  6); x1 ^= x0;
  x0 += k0; x1 += k1 + 3u;
  x0 += x1; x1 = rotl32(x1, 17); x1 ^= x0;
  x0 += x1; x1 = rotl32(x1, 29); x1 ^= x0;
  x0 += x1; x1 = rotl32(x1, 16); x1 ^= x0;
  x0 += x1; x1 = rotl32(x1, 24); x1 ^= x0;
  x0 += k1; x1 += k2 + 4u;
  x0 += x1; x1 = rotl32(x1, 13); x1 ^= x0;
  x0 += x1; x1 = rotl32(x1, 15); x1 ^= x0;
  x0 += x1; x1 = rotl32(x1, 26); x1 ^= x0;
  x0 += x1; x1 = rotl32(x1,  6); x1 ^= x0;
  x0 += k2; x1 += k0 + 5u;
  o0 = x0; o1 = x1;
}

// f32(-log(x)) for a normal positive float x, via custom double-precision log.
// Range-reduce m in [sqrt(1/2), sqrt(2)); log(m) = 2z*P(z^2), z=(m-1)/(m+1).
// 8-term atanh series: rel err < 2^-44 -> f32-rounded result matches the
// correctly-rounded reference except ~2^-20 of inputs (1 ulp).
__device__ __forceinline__ float neg_log_f32(float xf) {
  uint32_t i = __float_as_uint(xf);
  int e = ((int)(i - 0x3f3504f3u)) >> 23;
  double m = (double)__uint_as_float(i - (uint32_t)(e << 23));
  double z = (m - 1.0) / (m + 1.0);
  double p = z * z;
  double poly = 0x1.1111111111111p-4;          // 1/15
  poly = fma(poly, p, 0x1.3b13b13b13b14p-4);   // 1/13
  poly = fma(poly, p, 0x1.745d1745d1746p-4);   // 1/11
  poly = fma(poly, p, 0x1.c71c71c71c71cp-4);   // 1/9
  poly = fma(poly, p, 0x1.2492492492492p-3);   // 1/7
  poly = fma(poly, p, 0x1.999999999999ap-3);   // 1/5
  poly = fma(poly, p, 0x1.5555555555555p-2);   // 1/3
  poly = fma(poly, p, 1.0);
  double r = fma(-2.0 * z, poly, (double)(-e) * 0x1.62e42fefa39efp-1);
  return (float)r;
}

__device__ __forceinline__ float gumbel_f32(uint32_t bits) {
  uint32_t m = bits >> 9;
  float u = (m == 0u) ? 1.17549435e-38f
                      : (__uint_as_float(m | 0x3f800000u) - 1.0f);
  float t = neg_log_f32(u);   // f32(-log(u))
  return neg_log_f32(t);      // f32(-log(t))
}

// ------------------------------- kernels -------------------------------------

// pair-interleaved transpose: float2 at [ (d>>1)*1024 + k ] = (w[k][2d'],w[k][2d'+1])
__global__ __launch_bounds__(256) void k_transpose(const float* __restrict__ w,
                                                   float* __restrict__ wT) {
  int id = blockIdx.x * 256 + threadIdx.x;   // < K*D
  int k = id >> 8, d = id & 255;
  wT[(d >> 1) * 2048 + k * 2 + (d & 1)] = w[id];
}

// sequential f32 sum of squares per row (mimic XLA:CPU minor-axis reduce)
__global__ __launch_bounds__(256) void k_rowsumsq(const float* __restrict__ a,
                                                  float* __restrict__ outp,
                                                  int rows) {
  int r = blockIdx.x * blockDim.x + threadIdx.x;
  if (r >= rows) return;
  const float* p = a + (size_t)r * DIM;
  float acc = 0.0f;
  for (int i = 0; i < DIM; ++i) {
    float pi = p[i];
    acc = __fadd_rn(acc, __fmul_rn(pi, pi));
  }
  outp[r] = acc;
}

// one block per row n: exact-f64 dots vs all K codes, then S gumbel-argmax samples
__global__ __launch_bounds__(256) void k_sample(const float* __restrict__ x,
                                                const float* __restrict__ wT,
                                                const float* __restrict__ wsum,
                                                const float* __restrict__ xsum,
                                                int* __restrict__ samples,
                                                int* __restrict__ cnt) {
  int n = blockIdx.x;
  int t = threadIdx.x;
  __shared__ double xrowd[DIM];
  __shared__ float vred[4];
  __shared__ int   kred[4];

  xrowd[t] = (double)x[(size_t)n * DIM + t];
  __syncthreads();

  const float2* w2 = (const float2*)wT;   // [128][1024] float2
  double acc0 = 0.0, acc1 = 0.0, acc2 = 0.0, acc3 = 0.0;
#pragma unroll 4
  for (int d2 = 0; d2 < 128; ++d2) {
    double xa = xrowd[2 * d2];
    double xb = xrowd[2 * d2 + 1];
    const float2* p = w2 + (size_t)d2 * 1024 + t;
    float2 f0 = p[0];
    float2 f1 = p[256];
    float2 f2 = p[512];
    float2 f3 = p[768];
    acc0 = fma(xb, (double)f0.y, fma(xa, (double)f0.x, acc0));
    acc1 = fma(xb, (double)f1.y, fma(xa, (double)f1.x, acc1));
    acc2 = fma(xb, (double)f2.y, fma(xa, (double)f2.x, acc2));
    acc3 = fma(xb, (double)f3.y, fma(xa, (double)f3.x, acc3));
  }
  float xs = xsum[n];
  // logits = -(f32(wsum_k + xsum_n) - f32(2*dot)) ; -(a-b) == (b-a) in IEEE
  float l0 = __fsub_rn(__fmul_rn(2.0f, (float)acc0), __fadd_rn(wsum[t],       xs));
  float l1 = __fsub_rn(__fmul_rn(2.0f, (float)acc1), __fadd_rn(wsum[t + 256], xs));
  float l2 = __fsub_rn(__fmul_rn(2.0f, (float)acc2), __fadd_rn(wsum[t + 512], xs));
  float l3 = __fsub_rn(__fmul_rn(2.0f, (float)acc3), __fadd_rn(wsum[t + 768], xs));

  for (int s = 0; s < NSAMP; ++s) {
    uint32_t fbase = ((uint32_t)s * (uint32_t)NV + (uint32_t)n) * (uint32_t)KCB;
    uint32_t a0, a1, b0, b1, c0, c1, d0, d1;
    threefry2x32(0u, fbase + (uint32_t)t,        a0, a1);
    threefry2x32(0u, fbase + (uint32_t)t + 256u, b0, b1);
    threefry2x32(0u, fbase + (uint32_t)t + 512u, c0, c1);
    threefry2x32(0u, fbase + (uint32_t)t + 768u, d0, d1);
    float va = __fadd_rn(gumbel_f32(a0 ^ a1), l0);
    float vb = __fadd_rn(gumbel_f32(b0 ^ b1), l1);
    float vc = __fadd_rn(gumbel_f32(c0 ^ c1), l2);
    float vd = __fadd_rn(gumbel_f32(d0 ^ d1), l3);

    // per-thread best over ascending k (strict > keeps first max)
    float best = va; int bk = t;
    if (vb > best) { best = vb; bk = t + 256; }
    if (vc > best) { best = vc; bk = t + 512; }
    if (vd > best) { best = vd; bk = t + 768; }

    // wave butterfly reduce: order = (v desc, k asc)
#pragma unroll
    for (int off = 1; off < 64; off <<= 1) {
      float v2 = __shfl_xor(best, off, 64);
      int   k2 = __shfl_xor(bk,   off, 64);
      if (v2 > best || (v2 == best && k2 < bk)) { best = v2; bk = k2; }
    }
    if ((t & 63) == 0) { vred[t >> 6] = best; kred[t >> 6] = bk; }
    __syncthreads();
    if (t == 0) {
#pragma unroll
      for (int w = 1; w < 4; ++w) {
        float v2 = vred[w]; int k2 = kred[w];
        if (v2 > best || (v2 == best && k2 < bk)) { best = v2; bk = k2; }
      }
      samples[s * NV + n] = bk;
      atomicAdd(&cnt[bk], 1);
    }
    __syncthreads();
  }
}

// accumulate sum of x vectors per selected code (f64 atomics)
__global__ __launch_bounds__(256) void k_scatter(const float* __restrict__ x,
                                                 const int* __restrict__ samples,
                                                 double* __restrict__ sumx) {
  int n = blockIdx.x, t = threadIdx.x;
  double xv = (double)x[(size_t)n * DIM + t];
  for (int s = 0; s < NSAMP; ++s) {
    int k = samples[s * NV + n];
    __hip_atomic_fetch_add(&sumx[(size_t)k * DIM + t], xv,
                           __ATOMIC_RELAXED, __HIP_MEMORY_SCOPE_AGENT);
  }
}

// finalize counts (normalized), perplexity
__global__ __launch_bounds__(1024) void k_cfinal(const float* __restrict__ ema_count,
                                                 const int* __restrict__ cnt,
                                                 double* __restrict__ ncn64,
                                                 float* __restrict__ out_count,
                                                 float* __restrict__ out_perp) {
  __shared__ double red[1024];
  int k = threadIdx.x;
  double ec = (double)cnt[k] * 0.2;                       // column sum of encodings
  double nc0 = 0.999 * (double)ema_count[k] + 0.001 * ec;
  red[k] = nc0;
  __syncthreads();
  for (int off = 512; off > 0; off >>= 1) {
    if (k < off) red[k] += red[k + off];
    __syncthreads();
  }
  double ntot = red[0];
  __syncthreads();
  double ncn = (nc0 + 1e-5) / (ntot + (double)KCB * 1e-5) * ntot;
  ncn64[k] = ncn;
  out_count[k] = (float)ncn;

  double avg = ec / (double)NV;
  red[k] = avg * log(avg + 1e-10);
  __syncthreads();
  for (int off = 512; off > 0; off >>= 1) {
    if (k < off) red[k] += red[k + off];
    __syncthreads();
  }
  if (k == 0) out_perp[0] = (float)exp(-red[0]);
}

// new_weight, new_embedding
__global__ __launch_bounds__(256) void k_weight(const float* __restrict__ ema_w,
                                                const double* __restrict__ sumx,
                                                const double* __restrict__ ncn64,
                                                float* __restrict__ out_w,
                                                float* __restrict__ out_emb,
                                                float* __restrict__ emb32) {
  int k = blockIdx.x, d = threadIdx.x;
  size_t i = (size_t)k * DIM + d;
  double dw = 0.2 * sumx[i];
  double nw = 0.999 * (double)ema_w[i] + 0.001 * dw;
  float nw32 = (float)nw;
  float e = __fdiv_rn(nw32, (float)ncn64[k]);
  out_w[i] = nw32;
  out_emb[i] = e;
  emb32[i] = e;
}

// quantized_st + latent-loss partial sums
__global__ __launch_bounds__(256) void k_quant(const float* __restrict__ x,
                                               const int* __restrict__ samples,
                                               const float* __restrict__ emb32,
                                               float* __restrict__ out_q,
                                               double* __restrict__ lossacc) {
  int n = blockIdx.x, t = threadIdx.x;
  __shared__ int s5[NSAMP];
  __shared__ double wsum4[4];
  if (t < NSAMP) s5[t] = samples[t * NV + n];
  __syncthreads();
  float xv = x[(size_t)n * DIM + t];
  float acc = emb32[(size_t)s5[0] * DIM + t];
  for (int s = 1; s < NSAMP; ++s)
    acc = __fadd_rn(acc, emb32[(size_t)s5[s] * DIM + t]);
  float q = __fdiv_rn(acc, 5.0f);
  out_q[(size_t)n * DIM + t] = __fadd_rn(xv, __fsub_rn(q, xv));
  float df = __fsub_rn(xv, q);
  double v = (double)df * (double)df;
  for (int off = 32; off > 0; off >>= 1) v += __shfl_down(v, off);
  int wid = t >> 6, lane = t & 63;
  if (lane == 0) wsum4[wid] = v;
  __syncthreads();
  if (t == 0) {
    double b = wsum4[0] + wsum4[1] + wsum4[2] + wsum4[3];
    __hip_atomic_fetch_add(lossacc, b, __ATOMIC_RELAXED, __HIP_MEMORY_SCOPE_AGENT);
  }
}

__global__ void k_loss(const double* __restrict__ lossacc,
                       float* __restrict__ out_loss) {
  out_loss[0] = (float)(0.25 * (lossacc[0] / (double)(NV * DIM)));
}

// ------------------------------- launcher ------------------------------------
extern "C" void kernel_launch(void* const* d_in, const int* in_sizes, int n_in,
                              void* d_out, int out_size, void* d_ws, size_t ws_size,
                              hipStream_t stream) {
  const float* x     = (const float*)d_in[0];   // [64,512,256]
  const float* emb   = (const float*)d_in[1];   // [1024,256]
  const float* ema_c = (const float*)d_in[2];   // [1024]
  const float* ema_w = (const float*)d_in[3];   // [1024,256]

  float* out      = (float*)d_out;
  float* out_q    = out;                 // 8,388,608
  float* out_loss = out + 8388608;       // 1
  float* out_perp = out + 8388609;       // 1
  float* out_emb  = out + 8388610;       // 262,144
  float* out_cnt  = out + 8650754;       // 1,024
  float* out_w    = out + 8651778;       // 262,144  (end 8,913,922)

  char* ws = (char*)d_ws;
  float*  wT      = (float*)(ws + 0);         // 1,048,576 B (pair-interleaved)
  float*  wsum    = (float*)(ws + 1048576);   // 4,096 B
  float*  xsum    = (float*)(ws + 1052672);   // 131,072 B
  int*    samples = (int*)  (ws + 1183744);   // 655,360 B
  int*    cnt     = (int*)  (ws + 1839104);   // 4,096 B   (zeroed)
  double* sumx    = (double*)(ws + 1843200);  // 2,097,152 B (zeroed)
  double* lossacc = (double*)(ws + 3940352);  // 8 B       (zeroed)
  double* ncn64   = (double*)(ws + 3940360);  // 8,192 B
  float*  emb32   = (float*)(ws + 3948552);   // 1,048,576 B

  // zero the accumulators (cnt + sumx + lossacc are contiguous)
  hipMemsetAsync(ws + 1839104, 0, 4096 + 2097152 + 8, stream);

  k_transpose<<<KCB * DIM / 256, 256, 0, stream>>>(emb, wT);
  k_rowsumsq<<<KCB / 256, 256, 0, stream>>>(emb, wsum, KCB);
  k_rowsumsq<<<NV / 256, 256, 0, stream>>>(x, xsum, NV);
  k_sample<<<NV, 256, 0, stream>>>(x, wT, wsum, xsum, samples, cnt);
  k_scatter<<<NV, 256, 0, stream>>>(x, samples, sumx);
  k_cfinal<<<1, 1024, 0, stream>>>(ema_c, cnt, ncn64, out_cnt, out_perp);
  k_weight<<<KCB, 256, 0, stream>>>(ema_w, sumx, ncn64, out_w, out_emb, emb32);
  k_quant<<<NV, 256, 0, stream>>>(x, samples, emb32, out_q, lossacc);
  k_loss<<<1, 1, 0, stream>>>(lossacc, out_loss);
}

// Round 3
// 1564.064 us; speedup vs baseline: 1.7218x; 1.6158x over previous
//
#include <hip/hip_runtime.h>
#include <stdint.h>
#include <math.h>

#define NV 32768      // N = B*T
#define DIM 256       // D
#define KCB 1024      // K
#define NSAMP 5       // S

typedef double f64x4 __attribute__((ext_vector_type(4)));

// ---------------- threefry2x32 (20 rounds), JAX key = (0, 42) ----------------
__device__ __forceinline__ uint32_t rotl32(uint32_t v, int r) {
  return (v << r) | (v >> (32 - r));
}

__device__ __forceinline__ void threefry2x32(uint32_t c0, uint32_t c1,
                                             uint32_t& o0, uint32_t& o1) {
  const uint32_t k0 = 0u, k1 = 42u;
  const uint32_t k2 = k0 ^ k1 ^ 0x1BD11BDAu;
  uint32_t x0 = c0 + k0, x1 = c1 + k1;
  x0 += x1; x1 = rotl32(x1, 13); x1 ^= x0;
  x0 += x1; x1 = rotl32(x1, 15); x1 ^= x0;
  x0 += x1; x1 = rotl32(x1, 26); x1 ^= x0;
  x0 += x1; x1 = rotl32(x1,  6); x1 ^= x0;
  x0 += k1; x1 += k2 + 1u;
  x0 += x1; x1 = rotl32(x1, 17); x1 ^= x0;
  x0 += x1; x1 = rotl32(x1, 29); x1 ^= x0;
  x0 += x1; x1 = rotl32(x1, 16); x1 ^= x0;
  x0 += x1; x1 = rotl32(x1, 24); x1 ^= x0;
  x0 += k2; x1 += k0 + 2u;
  x0 += x1; x1 = rotl32(x1, 13); x1 ^= x0;
  x0 += x1; x1 = rotl32(x1, 15); x1 ^= x0;
  x0 += x1; x1 = rotl32(x1, 26); x1 ^= x0;
  x0 += x1; x1 = rotl32(x1,  6); x1 ^= x0;
  x0 += k0; x1 += k1 + 3u;
  x0 += x1; x1 = rotl32(x1, 17); x1 ^= x0;
  x0 += x1; x1 = rotl32(x1, 29); x1 ^= x0;
  x0 += x1; x1 = rotl32(x1, 16); x1 ^= x0;
  x0 += x1; x1 = rotl32(x1, 24); x1 ^= x0;
  x0 += k1; x1 += k2 + 4u;
  x0 += x1; x1 = rotl32(x1, 13); x1 ^= x0;
  x0 += x1; x1 = rotl32(x1, 15); x1 ^= x0;
  x0 += x1; x1 = rotl32(x1, 26); x1 ^= x0;
  x0 += x1; x1 = rotl32(x1,  6); x1 ^= x0;
  x0 += k2; x1 += k0 + 5u;
  o0 = x0; o1 = x1;
}

// f32(-log(x)) via custom f64 log (rel err < 2^-44) — bit-compatible with
// the correctly-rounded reference logf (validated R1/R2: zero sample flips).
__device__ __forceinline__ float neg_log_f32(float xf) {
  uint32_t i = __float_as_uint(xf);
  int e = ((int)(i - 0x3f3504f3u)) >> 23;
  double m = (double)__uint_as_float(i - (uint32_t)(e << 23));
  double z = (m - 1.0) / (m + 1.0);
  double p = z * z;
  double poly = 0x1.1111111111111p-4;          // 1/15
  poly = fma(poly, p, 0x1.3b13b13b13b14p-4);   // 1/13
  poly = fma(poly, p, 0x1.745d1745d1746p-4);   // 1/11
  poly = fma(poly, p, 0x1.c71c71c71c71cp-4);   // 1/9
  poly = fma(poly, p, 0x1.2492492492492p-3);   // 1/7
  poly = fma(poly, p, 0x1.999999999999ap-3);   // 1/5
  poly = fma(poly, p, 0x1.5555555555555p-2);   // 1/3
  poly = fma(poly, p, 1.0);
  double r = fma(-2.0 * z, poly, (double)(-e) * 0x1.62e42fefa39efp-1);
  return (float)r;
}

__device__ __forceinline__ float gumbel_f32(uint32_t bits) {
  uint32_t m = bits >> 9;
  float u = (m == 0u) ? 1.17549435e-38f
                      : (__uint_as_float(m | 0x3f800000u) - 1.0f);
  float t = neg_log_f32(u);   // f32(-log(u))
  return neg_log_f32(t);      // f32(-log(t))
}

// ------------------------------- kernels -------------------------------------

// wT64[d][k] = (double)emb[k][d]; tiled 64x64 transpose, coalesced both sides
__global__ __launch_bounds__(256) void k_prep(const float* __restrict__ emb,
                                              double* __restrict__ wT64) {
  __shared__ float tile[64][65];
  int bk = blockIdx.x;        // k-tile 0..15
  int bd = blockIdx.y;        // d-tile 0..3
  int t = threadIdx.x;
  int tr = t >> 6, tc = t & 63;
#pragma unroll
  for (int i = 0; i < 16; ++i) {
    int kk = tr + i * 4;
    tile[kk][tc] = emb[(size_t)(bk * 64 + kk) * 256 + bd * 64 + tc];
  }
  __syncthreads();
#pragma unroll
  for (int i = 0; i < 16; ++i) {
    int dd = tr + i * 4;
    wT64[(size_t)(bd * 64 + dd) * 1024 + bk * 64 + tc] = (double)tile[tc][dd];
  }
}

// sequential f32 sum of squares per row (mimic XLA:CPU minor-axis reduce)
__global__ __launch_bounds__(256) void k_rowsumsq(const float* __restrict__ a,
                                                  float* __restrict__ outp,
                                                  int rows) {
  int r = blockIdx.x * blockDim.x + threadIdx.x;
  if (r >= rows) return;
  const float* p = a + (size_t)r * DIM;
  float acc = 0.0f;
  for (int i = 0; i < DIM; ++i) {
    float pi = p[i];
    acc = __fadd_rn(acc, __fmul_rn(pi, pi));
  }
  outp[r] = acc;
}

// Fused: per block of 16 rows — MFMA f64 logits (k-chunked into LDS) + gumbel
// sampling with running argmax, then cross-thread reduce.
__global__ __launch_bounds__(256) void k_fused(const float* __restrict__ x,
                                               const double* __restrict__ wT64,
                                               const float* __restrict__ wsum,
                                               const float* __restrict__ xsum,
                                               int* __restrict__ samples,
                                               int* __restrict__ cnt) {
  __shared__ float xl[16 * 260];     // x tile, padded stride 260 (bank-safe)
  __shared__ float ll[256 * 17];     // logits chunk [k_local][row], stride 17
  __shared__ float xs[16];
  __shared__ float vred[4 * 16 * 5];
  __shared__ int   kred[4 * 16 * 5];

  int nb = blockIdx.x;               // row-tile index (16 rows)
  int t = threadIdx.x;
  int lane = t & 63, wv = t >> 6;
  int m = lane & 15, g = lane >> 4;  // MFMA roles: A-row / K-dim group
  int r = t & 15, kg = t >> 4;       // sampling roles: row / k-group

  // stage x tile (16 rows x 256 f32), coalesced
#pragma unroll
  for (int i = 0; i < 16; ++i)
    xl[i * 260 + t] = x[((size_t)nb * 16 + i) * 256 + t];
  if (t < 16) xs[t] = xsum[nb * 16 + t];
  __syncthreads();

  float bb[5];
  int   kk[5];
#pragma unroll
  for (int s = 0; s < 5; ++s) { bb[s] = -INFINITY; kk[s] = 0; }
  uint32_t rowbase = ((uint32_t)nb * 16u + (uint32_t)r) * 1024u;

  for (int ch = 0; ch < 4; ++ch) {
    // ---- GEMM phase: wave wv computes cols [wv*64, wv*64+64) of this chunk
    for (int ct = 0; ct < 4; ++ct) {
      int klocal = wv * 64 + ct * 16 + m;
      int kglob = ch * 256 + klocal;
      f64x4 C = {0.0, 0.0, 0.0, 0.0};
      const double* bp = wT64 + (size_t)g * 1024 + kglob;  // d = step*4+g
      const float* ap = xl + m * 260 + g;
#pragma unroll 8
      for (int step = 0; step < 64; ++step) {
        double a = (double)ap[step * 4];
        double b = bp[(size_t)step * 4096];
        C = __builtin_amdgcn_mfma_f64_16x16x4f64(a, b, C, 0, 0, 0);
      }
      float ws_k = wsum[kglob];
#pragma unroll
      for (int j = 0; j < 4; ++j) {
        int row = g * 4 + j;
        float l32 = __fsub_rn(__fmul_rn(2.0f, (float)C[j]),
                              __fadd_rn(ws_k, xs[row]));
        ll[klocal * 17 + row] = l32;
      }
    }
    __syncthreads();

    // ---- sampling phase: thread (r, kg) scans k_local = kg + 16*i
#pragma unroll 1
    for (int i = 0; i < 16; ++i) {
      int kl = kg + (i << 4);
      float lv = ll[kl * 17 + r];
      int gki = (ch << 8) + kl;            // ascending k per thread
      uint32_t cbase = rowbase + (uint32_t)gki;
#pragma unroll
      for (int s = 0; s < 5; ++s) {
        uint32_t o0, o1;
        threefry2x32(0u, cbase + (uint32_t)s * 33554432u, o0, o1);
        float v = __fadd_rn(gumbel_f32(o0 ^ o1), lv);
        if (v > bb[s]) { bb[s] = v; kk[s] = gki; }
      }
    }
    __syncthreads();
  }

  // ---- reduce across the 16 threads sharing row r
  // intra-wave: lanes {r, r+16, r+32, r+48}
#pragma unroll
  for (int s = 0; s < 5; ++s) {
#pragma unroll
    for (int off = 16; off <= 32; off <<= 1) {
      float v2 = __shfl_xor(bb[s], off, 64);
      int   k2 = __shfl_xor(kk[s], off, 64);
      if (v2 > bb[s] || (v2 == bb[s] && k2 < kk[s])) { bb[s] = v2; kk[s] = k2; }
    }
  }
  if (g == 0) {  // lane == r
#pragma unroll
    for (int s = 0; s < 5; ++s) {
      vred[(wv * 16 + r) * 5 + s] = bb[s];
      kred[(wv * 16 + r) * 5 + s] = kk[s];
    }
  }
  __syncthreads();
  if (t < 80) {
    int rr = t / 5, s = t % 5;
    float best = vred[rr * 5 + s];
    int bk2 = kred[rr * 5 + s];
#pragma unroll
    for (int w = 1; w < 4; ++w) {
      float v2 = vred[(w * 16 + rr) * 5 + s];
      int   k2 = kred[(w * 16 + rr) * 5 + s];
      if (v2 > best || (v2 == best && k2 < bk2)) { best = v2; bk2 = k2; }
    }
    int n = nb * 16 + rr;
    samples[s * NV + n] = bk2;
    atomicAdd(&cnt[bk2], 1);
  }
}

// exclusive prefix sum of cnt -> offs, cursor
__global__ __launch_bounds__(1024) void k_offsets(const int* __restrict__ cnt,
                                                  int* __restrict__ offs,
                                                  int* __restrict__ cursor) {
  __shared__ int sc[1024];
  int k = threadIdx.x;
  int v = cnt[k];
  sc[k] = v;
  __syncthreads();
  for (int off = 1; off < 1024; off <<= 1) {
    int a = (k >= off) ? sc[k - off] : 0;
    __syncthreads();
    sc[k] += a;
    __syncthreads();
  }
  int excl = sc[k] - v;
  offs[k] = excl;
  cursor[k] = excl;
}

// scatter sample indices into per-k inverted lists
__global__ __launch_bounds__(256) void k_fill(const int* __restrict__ samples,
                                              int* __restrict__ cursor,
                                              uint32_t* __restrict__ list) {
  int idx = blockIdx.x * 256 + threadIdx.x;   // < 163840
  int k = samples[idx];
  int n = idx & (NV - 1);
  int pos = atomicAdd(&cursor[k], 1);
  list[pos] = (uint32_t)n;
}

// finalize counts (normalized), perplexity
__global__ __launch_bounds__(1024) void k_cfinal(const float* __restrict__ ema_count,
                                                 const int* __restrict__ cnt,
                                                 double* __restrict__ ncn64,
                                                 float* __restrict__ out_count,
                                                 float* __restrict__ out_perp) {
  __shared__ double red[1024];
  int k = threadIdx.x;
  double ec = (double)cnt[k] * 0.2;
  double nc0 = 0.999 * (double)ema_count[k] + 0.001 * ec;
  red[k] = nc0;
  __syncthreads();
  for (int off = 512; off > 0; off >>= 1) {
    if (k < off) red[k] += red[k + off];
    __syncthreads();
  }
  double ntot = red[0];
  __syncthreads();
  double ncn = (nc0 + 1e-5) / (ntot + (double)KCB * 1e-5) * ntot;
  ncn64[k] = ncn;
  out_count[k] = (float)ncn;

  double avg = ec / (double)NV;
  red[k] = avg * log(avg + 1e-10);
  __syncthreads();
  for (int off = 512; off > 0; off >>= 1) {
    if (k < off) red[k] += red[k + off];
    __syncthreads();
  }
  if (k == 0) out_perp[0] = (float)exp(-red[0]);
}

// per-k gather of selected x rows -> dw, new_weight, new_embedding
__global__ __launch_bounds__(256) void k_weight2(const float* __restrict__ x,
                                                 const float* __restrict__ ema_w,
                                                 const uint32_t* __restrict__ list,
                                                 const int* __restrict__ offs,
                                                 const int* __restrict__ cnt,
                                                 const double* __restrict__ ncn64,
                                                 float* __restrict__ out_w,
                                                 float* __restrict__ out_emb,
                                                 float* __restrict__ emb32) {
  int k = blockIdx.x, d = threadIdx.x;
  int base = offs[k], mcnt = cnt[k];
  double acc = 0.0;
  for (int i = 0; i < mcnt; ++i) {
    uint32_t n = list[base + i];
    acc += (double)x[(size_t)n * 256 + d];
  }
  double dw = 0.2 * acc;
  double nw = 0.999 * (double)ema_w[(size_t)k * 256 + d] + 0.001 * dw;
  float nw32 = (float)nw;
  float e = __fdiv_rn(nw32, (float)ncn64[k]);
  size_t i2 = (size_t)k * 256 + d;
  out_w[i2] = nw32;
  out_emb[i2] = e;
  emb32[i2] = e;
}

// quantized_st + latent-loss partial sums
__global__ __launch_bounds__(256) void k_quant(const float* __restrict__ x,
                                               const int* __restrict__ samples,
                                               const float* __restrict__ emb32,
                                               float* __restrict__ out_q,
                                               double* __restrict__ lossacc) {
  int n = blockIdx.x, t = threadIdx.x;
  __shared__ int s5[NSAMP];
  __shared__ double wsum4[4];
  if (t < NSAMP) s5[t] = samples[t * NV + n];
  __syncthreads();
  float xv = x[(size_t)n * DIM + t];
  float acc = emb32[(size_t)s5[0] * DIM + t];
  for (int s = 1; s < NSAMP; ++s)
    acc = __fadd_rn(acc, emb32[(size_t)s5[s] * DIM + t]);
  float q = __fdiv_rn(acc, 5.0f);
  out_q[(size_t)n * DIM + t] = __fadd_rn(xv, __fsub_rn(q, xv));
  float df = __fsub_rn(xv, q);
  double v = (double)df * (double)df;
  for (int off = 32; off > 0; off >>= 1) v += __shfl_down(v, off);
  int wid = t >> 6, lane = t & 63;
  if (lane == 0) wsum4[wid] = v;
  __syncthreads();
  if (t == 0) {
    double b = wsum4[0] + wsum4[1] + wsum4[2] + wsum4[3];
    __hip_atomic_fetch_add(lossacc, b, __ATOMIC_RELAXED, __HIP_MEMORY_SCOPE_AGENT);
  }
}

__global__ void k_loss(const double* __restrict__ lossacc,
                       float* __restrict__ out_loss) {
  out_loss[0] = (float)(0.25 * (lossacc[0] / (double)(NV * DIM)));
}

// ------------------------------- launcher ------------------------------------
extern "C" void kernel_launch(void* const* d_in, const int* in_sizes, int n_in,
                              void* d_out, int out_size, void* d_ws, size_t ws_size,
                              hipStream_t stream) {
  const float* x     = (const float*)d_in[0];   // [64,512,256]
  const float* emb   = (const float*)d_in[1];   // [1024,256]
  const float* ema_c = (const float*)d_in[2];   // [1024]
  const float* ema_w = (const float*)d_in[3];   // [1024,256]

  float* out      = (float*)d_out;
  float* out_q    = out;                 // 8,388,608
  float* out_loss = out + 8388608;       // 1
  float* out_perp = out + 8388609;       // 1
  float* out_emb  = out + 8388610;       // 262,144
  float* out_cnt  = out + 8650754;       // 1,024
  float* out_w    = out + 8651778;       // 262,144

  char* ws = (char*)d_ws;
  double*   wT64    = (double*)(ws + 0);          // 2,097,152 B
  float*    wsum    = (float*)(ws + 2097152);     // 4,096 B
  float*    xsum    = (float*)(ws + 2101248);     // 131,072 B
  int*      samples = (int*)(ws + 2232320);       // 655,360 B
  int*      cnt     = (int*)(ws + 2887680);       // 4,096 B   [zeroed]
  double*   lossacc = (double*)(ws + 2891776);    // 8 B       [zeroed]
  double*   ncn64   = (double*)(ws + 2891784);    // 8,192 B
  int*      offs    = (int*)(ws + 2899976);       // 4,096 B
  int*      cursor  = (int*)(ws + 2904072);       // 4,096 B
  uint32_t* list    = (uint32_t*)(ws + 2908168);  // 655,360 B
  float*    emb32   = (float*)(ws + 3563528);     // 1,048,576 B -> ~4.6 MB

  // zero cnt + lossacc (contiguous region)
  hipMemsetAsync(ws + 2887680, 0, 4096 + 8, stream);

  k_prep<<<dim3(16, 4), 256, 0, stream>>>(emb, wT64);
  k_rowsumsq<<<KCB / 256, 256, 0, stream>>>(emb, wsum, KCB);
  k_rowsumsq<<<NV / 256, 256, 0, stream>>>(x, xsum, NV);
  k_fused<<<NV / 16, 256, 0, stream>>>(x, wT64, wsum, xsum, samples, cnt);
  k_offsets<<<1, 1024, 0, stream>>>(cnt, offs, cursor);
  k_fill<<<NV * NSAMP / 256, 256, 0, stream>>>(samples, cursor, list);
  k_cfinal<<<1, 1024, 0, stream>>>(ema_c, cnt, ncn64, out_cnt, out_perp);
  k_weight2<<<KCB, 256, 0, stream>>>(x, ema_w, list, offs, cnt, ncn64,
                                     out_w, out_emb, emb32);
  k_quant<<<NV, 256, 0, stream>>>(x, samples, emb32, out_q, lossacc);
  k_loss<<<1, 1, 0, stream>>>(lossacc, out_loss);
}

// Round 4
// 1306.049 us; speedup vs baseline: 2.0620x; 1.1976x over previous
//
#include <hip/hip_runtime.h>
#include <stdint.h>
#include <math.h>

#define NV 32768      // N = B*T
#define DIM 256       // D
#define KCB 1024      // K
#define NSAMP 5       // S

typedef double f64x4 __attribute__((ext_vector_type(4)));

// ---------------- threefry2x32 (20 rounds), JAX key = (0, 42) ----------------
__device__ __forceinline__ uint32_t rotl32(uint32_t v, int r) {
  return (v << r) | (v >> (32 - r));
}

__device__ __forceinline__ void threefry2x32(uint32_t c0, uint32_t c1,
                                             uint32_t& o0, uint32_t& o1) {
  const uint32_t k0 = 0u, k1 = 42u;
  const uint32_t k2 = k0 ^ k1 ^ 0x1BD11BDAu;
  uint32_t x0 = c0 + k0, x1 = c1 + k1;
  x0 += x1; x1 = rotl32(x1, 13); x1 ^= x0;
  x0 += x1; x1 = rotl32(x1, 15); x1 ^= x0;
  x0 += x1; x1 = rotl32(x1, 26); x1 ^= x0;
  x0 += x1; x1 = rotl32(x1,  6); x1 ^= x0;
  x0 += k1; x1 += k2 + 1u;
  x0 += x1; x1 = rotl32(x1, 17); x1 ^= x0;
  x0 += x1; x1 = rotl32(x1, 29); x1 ^= x0;
  x0 += x1; x1 = rotl32(x1, 16); x1 ^= x0;
  x0 += x1; x1 = rotl32(x1, 24); x1 ^= x0;
  x0 += k2; x1 += k0 + 2u;
  x0 += x1; x1 = rotl32(x1, 13); x1 ^= x0;
  x0 += x1; x1 = rotl32(x1, 15); x1 ^= x0;
  x0 += x1; x1 = rotl32(x1, 26); x1 ^= x0;
  x0 += x1; x1 = rotl32(x1,  6); x1 ^= x0;
  x0 += k0; x1 += k1 + 3u;
  x0 += x1; x1 = rotl32(x1, 17); x1 ^= x0;
  x0 += x1; x1 = rotl32(x1, 29); x1 ^= x0;
  x0 += x1; x1 = rotl32(x1, 16); x1 ^= x0;
  x0 += x1; x1 = rotl32(x1, 24); x1 ^= x0;
  x0 += k1; x1 += k2 + 4u;
  x0 += x1; x1 = rotl32(x1, 13); x1 ^= x0;
  x0 += x1; x1 = rotl32(x1, 15); x1 ^= x0;
  x0 += x1; x1 = rotl32(x1, 26); x1 ^= x0;
  x0 += x1; x1 = rotl32(x1,  6); x1 ^= x0;
  x0 += k2; x1 += k0 + 5u;
  o0 = x0; o1 = x1;
}

// exact path: f32(-log(x)) via f64 log (rel err < 2^-44) — bit-compatible with
// the correctly-rounded reference logf (validated R1-R3).
__device__ __forceinline__ float neg_log_f32(float xf) {
  uint32_t i = __float_as_uint(xf);
  int e = ((int)(i - 0x3f3504f3u)) >> 23;
  double m = (double)__uint_as_float(i - (uint32_t)(e << 23));
  double z = (m - 1.0) / (m + 1.0);
  double p = z * z;
  double poly = 0x1.1111111111111p-4;          // 1/15
  poly = fma(poly, p, 0x1.3b13b13b13b14p-4);   // 1/13
  poly = fma(poly, p, 0x1.745d1745d1746p-4);   // 1/11
  poly = fma(poly, p, 0x1.c71c71c71c71cp-4);   // 1/9
  poly = fma(poly, p, 0x1.2492492492492p-3);   // 1/7
  poly = fma(poly, p, 0x1.999999999999ap-3);   // 1/5
  poly = fma(poly, p, 0x1.5555555555555p-2);   // 1/3
  poly = fma(poly, p, 1.0);
  double r = fma(-2.0 * z, poly, (double)(-e) * 0x1.62e42fefa39efp-1);
  return (float)r;
}

__device__ __forceinline__ float u_from_bits(uint32_t bits) {
  uint32_t m = bits >> 9;
  return (m == 0u) ? 1.17549435e-38f
                   : (__uint_as_float(m | 0x3f800000u) - 1.0f);
}

__device__ __forceinline__ float gumbel_exact(uint32_t bits) {
  float u = u_from_bits(bits);
  float t = neg_log_f32(u);
  return neg_log_f32(t);
}

// screening approximation: |g_approx - g_exact| <= ~1e-6 (v_log_f32 is 1-ulp)
__device__ __forceinline__ float gumbel_approx(uint32_t bits) {
  float u = u_from_bits(bits);
  float t = __log2f(u) * (-0.6931471805599453f);   // ~ -log(u), > 0
  return __log2f(t) * (-0.6931471805599453f);      // ~ -log(t)
}

#define E2G 4e-5f   // near-tie window (>> 2x approx error, ~40x margin)

// ------------------------------- kernels -------------------------------------

// wT64[d][k] = (double)emb[k][d]; tiled 64x64 transpose, coalesced both sides
__global__ __launch_bounds__(256) void k_prep(const float* __restrict__ emb,
                                              double* __restrict__ wT64) {
  __shared__ float tile[64][65];
  int bk = blockIdx.x;        // k-tile 0..15
  int bd = blockIdx.y;        // d-tile 0..3
  int t = threadIdx.x;
  int tr = t >> 6, tc = t & 63;
#pragma unroll
  for (int i = 0; i < 16; ++i) {
    int kk = tr + i * 4;
    tile[kk][tc] = emb[(size_t)(bk * 64 + kk) * 256 + bd * 64 + tc];
  }
  __syncthreads();
#pragma unroll
  for (int i = 0; i < 16; ++i) {
    int dd = tr + i * 4;
    wT64[(size_t)(bd * 64 + dd) * 1024 + bk * 64 + tc] = (double)tile[tc][dd];
  }
}

// sequential f32 sum of squares per row (mimic XLA:CPU minor-axis reduce)
__global__ __launch_bounds__(256) void k_rowsumsq(const float* __restrict__ a,
                                                  float* __restrict__ outp,
                                                  int rows) {
  int r = blockIdx.x * blockDim.x + threadIdx.x;
  if (r >= rows) return;
  const float* p = a + (size_t)r * DIM;
  float acc = 0.0f;
  for (int i = 0; i < DIM; ++i) {
    float pi = p[i];
    acc = __fadd_rn(acc, __fmul_rn(pi, pi));
  }
  outp[r] = acc;
}

// Fused: per block of 16 rows — MFMA f64 logits (k-chunked into LDS) +
// approx-screened gumbel argmax (exact resolution of winner/runner only).
__global__ __launch_bounds__(256) void k_fused(const float* __restrict__ x,
                                               const double* __restrict__ wT64,
                                               const float* __restrict__ wsum,
                                               const float* __restrict__ xsum,
                                               int* __restrict__ samples,
                                               int* __restrict__ cnt) {
  __shared__ float xl[16 * 260];     // x tile, padded stride 260
  __shared__ float ll[256 * 17];     // logits chunk [k_local][row], stride 17
  __shared__ float xs[16];
  __shared__ float vred[4 * 16 * 5];
  __shared__ int   kred[4 * 16 * 5];

  int nb = blockIdx.x;               // row-tile index (16 rows)
  int t = threadIdx.x;
  int lane = t & 63, wv = t >> 6;
  int m = lane & 15, g = lane >> 4;  // MFMA roles: A-row / K-dim group
  int r = t & 15, kg = t >> 4;       // sampling roles: row / k-group

#pragma unroll
  for (int i = 0; i < 16; ++i)
    xl[i * 260 + t] = x[((size_t)nb * 16 + i) * 256 + t];
  if (t < 16) xs[t] = xsum[nb * 16 + t];
  __syncthreads();

  // winner/runner state per sample
  float    wvt[NSAMP], wlv[NSAMP], rlv[NSAMP];
  int      wk[NSAMP], rk[NSAMP];
  uint32_t wbits[NSAMP], rbits[NSAMP];
  uint32_t rvmask = 0;
#pragma unroll
  for (int s = 0; s < NSAMP; ++s) {
    wvt[s] = -INFINITY; wlv[s] = 0.f; wk[s] = 0; wbits[s] = 0u;
    rlv[s] = 0.f; rk[s] = 0; rbits[s] = 0u;
  }
  uint32_t rowbase = ((uint32_t)nb * 16u + (uint32_t)r) * 1024u;

  for (int ch = 0; ch < 4; ++ch) {
    // ---- GEMM phase: wave wv computes cols [wv*64, wv*64+64) of this chunk
    for (int ct = 0; ct < 4; ++ct) {
      int klocal = wv * 64 + ct * 16 + m;
      int kglob = ch * 256 + klocal;
      f64x4 C = {0.0, 0.0, 0.0, 0.0};
      const double* bp = wT64 + (size_t)g * 1024 + kglob;  // d = step*4+g
      const float* ap = xl + m * 260 + g;
#pragma unroll 8
      for (int step = 0; step < 64; ++step) {
        double a = (double)ap[step * 4];
        double b = bp[(size_t)step * 4096];
        C = __builtin_amdgcn_mfma_f64_16x16x4f64(a, b, C, 0, 0, 0);
      }
      float ws_k = wsum[kglob];
#pragma unroll
      for (int j = 0; j < 4; ++j) {
        int row = g * 4 + j;
        float l32 = __fsub_rn(__fmul_rn(2.0f, (float)C[j]),
                              __fadd_rn(ws_k, xs[row]));
        ll[klocal * 17 + row] = l32;
      }
    }
    __syncthreads();

    // ---- sampling phase: thread (r, kg) scans k_local = kg + 16*i (k asc)
#pragma unroll 1
    for (int i = 0; i < 16; ++i) {
      int kl = kg + (i << 4);
      float lv = ll[kl * 17 + r];
      int gki = (ch << 8) + kl;
      uint32_t cbase = rowbase + (uint32_t)gki;
#pragma unroll
      for (int s = 0; s < NSAMP; ++s) {
        uint32_t o0, o1;
        threefry2x32(0u, cbase + (uint32_t)s * 33554432u, o0, o1);
        uint32_t bits = o0 ^ o1;
        float vt = __fadd_rn(gumbel_approx(bits), lv);
        if (vt > wvt[s]) {
          if (wvt[s] > vt - E2G) {   // old winner still in contention
            rk[s] = wk[s]; rbits[s] = wbits[s]; rlv[s] = wlv[s];
            rvmask |= (1u << s);
          }
          wvt[s] = vt; wk[s] = gki; wbits[s] = bits; wlv[s] = lv;
        } else if (vt > wvt[s] - E2G) {   // near-tie below winner
          rk[s] = gki; rbits[s] = bits; rlv[s] = lv;
          rvmask |= (1u << s);
        }
      }
    }
    __syncthreads();
  }

  // ---- exact resolution of winner (+ rare runner), then cross-thread reduce
#pragma unroll
  for (int s = 0; s < NSAMP; ++s) {
    float ev = __fadd_rn(gumbel_exact(wbits[s]), wlv[s]);
    int ek = wk[s];
    if (rvmask & (1u << s)) {
      float er = __fadd_rn(gumbel_exact(rbits[s]), rlv[s]);
      if (er > ev || (er == ev && rk[s] < ek)) { ev = er; ek = rk[s]; }
    }
    // intra-wave: lanes {r, r+16, r+32, r+48}
#pragma unroll
    for (int off = 16; off <= 32; off <<= 1) {
      float v2 = __shfl_xor(ev, off, 64);
      int   k2 = __shfl_xor(ek, off, 64);
      if (v2 > ev || (v2 == ev && k2 < ek)) { ev = v2; ek = k2; }
    }
    if (g == 0) {  // lane == r
      vred[(wv * 16 + r) * 5 + s] = ev;
      kred[(wv * 16 + r) * 5 + s] = ek;
    }
  }
  __syncthreads();
  if (t < 80) {
    int rr = t / 5, s = t % 5;
    float best = vred[rr * 5 + s];
    int bk2 = kred[rr * 5 + s];
#pragma unroll
    for (int w = 1; w < 4; ++w) {
      float v2 = vred[(w * 16 + rr) * 5 + s];
      int   k2 = kred[(w * 16 + rr) * 5 + s];
      if (v2 > best || (v2 == best && k2 < bk2)) { best = v2; bk2 = k2; }
    }
    int n = nb * 16 + rr;
    samples[s * NV + n] = bk2;
    atomicAdd(&cnt[bk2], 1);
  }
}

// exclusive prefix sum of cnt -> offs, cursor
__global__ __launch_bounds__(1024) void k_offsets(const int* __restrict__ cnt,
                                                  int* __restrict__ offs,
                                                  int* __restrict__ cursor) {
  __shared__ int sc[1024];
  int k = threadIdx.x;
  int v = cnt[k];
  sc[k] = v;
  __syncthreads();
  for (int off = 1; off < 1024; off <<= 1) {
    int a = (k >= off) ? sc[k - off] : 0;
    __syncthreads();
    sc[k] += a;
    __syncthreads();
  }
  int excl = sc[k] - v;
  offs[k] = excl;
  cursor[k] = excl;
}

// scatter sample indices into per-k inverted lists
__global__ __launch_bounds__(256) void k_fill(const int* __restrict__ samples,
                                              int* __restrict__ cursor,
                                              uint32_t* __restrict__ list) {
  int idx = blockIdx.x * 256 + threadIdx.x;   // < 163840
  int k = samples[idx];
  int n = idx & (NV - 1);
  int pos = atomicAdd(&cursor[k], 1);
  list[pos] = (uint32_t)n;
}

// finalize counts (normalized), perplexity
__global__ __launch_bounds__(1024) void k_cfinal(const float* __restrict__ ema_count,
                                                 const int* __restrict__ cnt,
                                                 double* __restrict__ ncn64,
                                                 float* __restrict__ out_count,
                                                 float* __restrict__ out_perp) {
  __shared__ double red[1024];
  int k = threadIdx.x;
  double ec = (double)cnt[k] * 0.2;
  double nc0 = 0.999 * (double)ema_count[k] + 0.001 * ec;
  red[k] = nc0;
  __syncthreads();
  for (int off = 512; off > 0; off >>= 1) {
    if (k < off) red[k] += red[k + off];
    __syncthreads();
  }
  double ntot = red[0];
  __syncthreads();
  double ncn = (nc0 + 1e-5) / (ntot + (double)KCB * 1e-5) * ntot;
  ncn64[k] = ncn;
  out_count[k] = (float)ncn;

  double avg = ec / (double)NV;
  red[k] = avg * log(avg + 1e-10);
  __syncthreads();
  for (int off = 512; off > 0; off >>= 1) {
    if (k < off) red[k] += red[k + off];
    __syncthreads();
  }
  if (k == 0) out_perp[0] = (float)exp(-red[0]);
}

// per-k gather of selected x rows -> dw, new_weight, new_embedding
__global__ __launch_bounds__(256) void k_weight2(const float* __restrict__ x,
                                                 const float* __restrict__ ema_w,
                                                 const uint32_t* __restrict__ list,
                                                 const int* __restrict__ offs,
                                                 const int* __restrict__ cnt,
                                                 const double* __restrict__ ncn64,
                                                 float* __restrict__ out_w,
                                                 float* __restrict__ out_emb,
                                                 float* __restrict__ emb32) {
  int k = blockIdx.x, d = threadIdx.x;
  int base = offs[k], mcnt = cnt[k];
  double acc = 0.0;
  for (int i = 0; i < mcnt; ++i) {
    uint32_t n = list[base + i];
    acc += (double)x[(size_t)n * 256 + d];
  }
  double dw = 0.2 * acc;
  double nw = 0.999 * (double)ema_w[(size_t)k * 256 + d] + 0.001 * dw;
  float nw32 = (float)nw;
  float e = __fdiv_rn(nw32, (float)ncn64[k]);
  size_t i2 = (size_t)k * 256 + d;
  out_w[i2] = nw32;
  out_emb[i2] = e;
  emb32[i2] = e;
}

// quantized_st + latent-loss partial sums
__global__ __launch_bounds__(256) void k_quant(const float* __restrict__ x,
                                               const int* __restrict__ samples,
                                               const float* __restrict__ emb32,
                                               float* __restrict__ out_q,
                                               double* __restrict__ lossacc) {
  int n = blockIdx.x, t = threadIdx.x;
  __shared__ int s5[NSAMP];
  __shared__ double wsum4[4];
  if (t < NSAMP) s5[t] = samples[t * NV + n];
  __syncthreads();
  float xv = x[(size_t)n * DIM + t];
  float acc = emb32[(size_t)s5[0] * DIM + t];
  for (int s = 1; s < NSAMP; ++s)
    acc = __fadd_rn(acc, emb32[(size_t)s5[s] * DIM + t]);
  float q = __fdiv_rn(acc, 5.0f);
  out_q[(size_t)n * DIM + t] = __fadd_rn(xv, __fsub_rn(q, xv));
  float df = __fsub_rn(xv, q);
  double v = (double)df * (double)df;
  for (int off = 32; off > 0; off >>= 1) v += __shfl_down(v, off);
  int wid = t >> 6, lane = t & 63;
  if (lane == 0) wsum4[wid] = v;
  __syncthreads();
  if (t == 0) {
    double b = wsum4[0] + wsum4[1] + wsum4[2] + wsum4[3];
    __hip_atomic_fetch_add(lossacc, b, __ATOMIC_RELAXED, __HIP_MEMORY_SCOPE_AGENT);
  }
}

__global__ void k_loss(const double* __restrict__ lossacc,
                       float* __restrict__ out_loss) {
  out_loss[0] = (float)(0.25 * (lossacc[0] / (double)(NV * DIM)));
}

// ------------------------------- launcher ------------------------------------
extern "C" void kernel_launch(void* const* d_in, const int* in_sizes, int n_in,
                              void* d_out, int out_size, void* d_ws, size_t ws_size,
                              hipStream_t stream) {
  const float* x     = (const float*)d_in[0];   // [64,512,256]
  const float* emb   = (const float*)d_in[1];   // [1024,256]
  const float* ema_c = (const float*)d_in[2];   // [1024]
  const float* ema_w = (const float*)d_in[3];   // [1024,256]

  float* out      = (float*)d_out;
  float* out_q    = out;                 // 8,388,608
  float* out_loss = out + 8388608;       // 1
  float* out_perp = out + 8388609;       // 1
  float* out_emb  = out + 8388610;       // 262,144
  float* out_cnt  = out + 8650754;       // 1,024
  float* out_w    = out + 8651778;       // 262,144

  char* ws = (char*)d_ws;
  double*   wT64    = (double*)(ws + 0);          // 2,097,152 B
  float*    wsum    = (float*)(ws + 2097152);     // 4,096 B
  float*    xsum    = (float*)(ws + 2101248);     // 131,072 B
  int*      samples = (int*)(ws + 2232320);       // 655,360 B
  int*      cnt     = (int*)(ws + 2887680);       // 4,096 B   [zeroed]
  double*   lossacc = (double*)(ws + 2891776);    // 8 B       [zeroed]
  double*   ncn64   = (double*)(ws + 2891784);    // 8,192 B
  int*      offs    = (int*)(ws + 2899976);       // 4,096 B
  int*      cursor  = (int*)(ws + 2904072);       // 4,096 B
  uint32_t* list    = (uint32_t*)(ws + 2908168);  // 655,360 B
  float*    emb32   = (float*)(ws + 3563528);     // 1,048,576 B

  hipMemsetAsync(ws + 2887680, 0, 4096 + 8, stream);

  k_prep<<<dim3(16, 4), 256, 0, stream>>>(emb, wT64);
  k_rowsumsq<<<KCB / 256, 256, 0, stream>>>(emb, wsum, KCB);
  k_rowsumsq<<<NV / 256, 256, 0, stream>>>(x, xsum, NV);
  k_fused<<<NV / 16, 256, 0, stream>>>(x, wT64, wsum, xsum, samples, cnt);
  k_offsets<<<1, 1024, 0, stream>>>(cnt, offs, cursor);
  k_fill<<<NV * NSAMP / 256, 256, 0, stream>>>(samples, cursor, list);
  k_cfinal<<<1, 1024, 0, stream>>>(ema_c, cnt, ncn64, out_cnt, out_perp);
  k_weight2<<<KCB, 256, 0, stream>>>(x, ema_w, list, offs, cnt, ncn64,
                                     out_w, out_emb, emb32);
  k_quant<<<NV, 256, 0, stream>>>(x, samples, emb32, out_q, lossacc);
  k_loss<<<1, 1, 0, stream>>>(lossacc, out_loss);
}

// Round 5
// 924.930 us; speedup vs baseline: 2.9116x; 1.4121x over previous
//
#include <hip/hip_runtime.h>
#include <stdint.h>
#include <math.h>

#define NV 32768      // N = B*T
#define DIM 256       // D
#define KCB 1024      // K
#define NSAMP 5       // S

typedef double f64x4 __attribute__((ext_vector_type(4)));

// ---------------- threefry2x32 (20 rounds), JAX key = (0, 42) ----------------
__device__ __forceinline__ uint32_t rotl32(uint32_t v, int r) {
  return (v << r) | (v >> (32 - r));
}

__device__ __forceinline__ void threefry2x32(uint32_t c0, uint32_t c1,
                                             uint32_t& o0, uint32_t& o1) {
  const uint32_t k0 = 0u, k1 = 42u;
  const uint32_t k2 = k0 ^ k1 ^ 0x1BD11BDAu;
  uint32_t x0 = c0 + k0, x1 = c1 + k1;
  x0 += x1; x1 = rotl32(x1, 13); x1 ^= x0;
  x0 += x1; x1 = rotl32(x1, 15); x1 ^= x0;
  x0 += x1; x1 = rotl32(x1, 26); x1 ^= x0;
  x0 += x1; x1 = rotl32(x1,  6); x1 ^= x0;
  x0 += k1; x1 += k2 + 1u;
  x0 += x1; x1 = rotl32(x1, 17); x1 ^= x0;
  x0 += x1; x1 = rotl32(x1, 29); x1 ^= x0;
  x0 += x1; x1 = rotl32(x1, 16); x1 ^= x0;
  x0 += x1; x1 = rotl32(x1, 24); x1 ^= x0;
  x0 += k2; x1 += k0 + 2u;
  x0 += x1; x1 = rotl32(x1, 13); x1 ^= x0;
  x0 += x1; x1 = rotl32(x1, 15); x1 ^= x0;
  x0 += x1; x1 = rotl32(x1, 26); x1 ^= x0;
  x0 += x1; x1 = rotl32(x1,  6); x1 ^= x0;
  x0 += k0; x1 += k1 + 3u;
  x0 += x1; x1 = rotl32(x1, 17); x1 ^= x0;
  x0 += x1; x1 = rotl32(x1, 29); x1 ^= x0;
  x0 += x1; x1 = rotl32(x1, 16); x1 ^= x0;
  x0 += x1; x1 = rotl32(x1, 24); x1 ^= x0;
  x0 += k1; x1 += k2 + 4u;
  x0 += x1; x1 = rotl32(x1, 13); x1 ^= x0;
  x0 += x1; x1 = rotl32(x1, 15); x1 ^= x0;
  x0 += x1; x1 = rotl32(x1, 26); x1 ^= x0;
  x0 += x1; x1 = rotl32(x1,  6); x1 ^= x0;
  x0 += k2; x1 += k0 + 5u;
  o0 = x0; o1 = x1;
}

// exact path: f32(-log(x)) via f64 log (rel err < 2^-44) — bit-compatible with
// the correctly-rounded reference logf (validated R1-R4).
__device__ __forceinline__ float neg_log_f32(float xf) {
  uint32_t i = __float_as_uint(xf);
  int e = ((int)(i - 0x3f3504f3u)) >> 23;
  double m = (double)__uint_as_float(i - (uint32_t)(e << 23));
  double z = (m - 1.0) / (m + 1.0);
  double p = z * z;
  double poly = 0x1.1111111111111p-4;          // 1/15
  poly = fma(poly, p, 0x1.3b13b13b13b14p-4);   // 1/13
  poly = fma(poly, p, 0x1.745d1745d1746p-4);   // 1/11
  poly = fma(poly, p, 0x1.c71c71c71c71cp-4);   // 1/9
  poly = fma(poly, p, 0x1.2492492492492p-3);   // 1/7
  poly = fma(poly, p, 0x1.999999999999ap-3);   // 1/5
  poly = fma(poly, p, 0x1.5555555555555p-2);   // 1/3
  poly = fma(poly, p, 1.0);
  double r = fma(-2.0 * z, poly, (double)(-e) * 0x1.62e42fefa39efp-1);
  return (float)r;
}

__device__ __forceinline__ float u_from_bits(uint32_t bits) {
  uint32_t m = bits >> 9;
  return (m == 0u) ? 1.17549435e-38f
                   : (__uint_as_float(m | 0x3f800000u) - 1.0f);
}

__device__ __forceinline__ float gumbel_exact(uint32_t bits) {
  float u = u_from_bits(bits);
  float t = neg_log_f32(u);
  return neg_log_f32(t);
}

// screening approximation: |g_approx - g_exact| <= ~1e-6 (v_log_f32 is 1-ulp)
__device__ __forceinline__ float gumbel_approx(uint32_t bits) {
  float u = u_from_bits(bits);
  float t = __log2f(u) * (-0.6931471805599453f);   // ~ -log(u), > 0
  return __log2f(t) * (-0.6931471805599453f);      // ~ -log(t)
}

#define E2G 4e-5f   // near-tie window (>> 2x approx error, ~40x margin)

// ------------------------------- prep kernels --------------------------------

// f32 transpose: wT[d*1024 + k] = emb[k*256 + d], tiled via LDS
__global__ __launch_bounds__(256) void k_prep32(const float* __restrict__ emb,
                                                float* __restrict__ wT) {
  __shared__ float tile[64][65];
  int bk = blockIdx.x;        // k-tile 0..15
  int bd = blockIdx.y;        // d-tile 0..3
  int t = threadIdx.x;
  int tr = t >> 6, tc = t & 63;
#pragma unroll
  for (int i = 0; i < 16; ++i) {
    int kk = tr + i * 4;
    tile[kk][tc] = emb[(size_t)(bk * 64 + kk) * 256 + bd * 64 + tc];
  }
  __syncthreads();
#pragma unroll
  for (int i = 0; i < 16; ++i) {
    int dd = tr + i * 4;
    wT[(size_t)(bd * 64 + dd) * 1024 + bk * 64 + tc] = tile[tc][dd];
  }
}

// f64 transpose (fused-fallback path)
__global__ __launch_bounds__(256) void k_prep64(const float* __restrict__ emb,
                                                double* __restrict__ wT64) {
  __shared__ float tile[64][65];
  int bk = blockIdx.x;
  int bd = blockIdx.y;
  int t = threadIdx.x;
  int tr = t >> 6, tc = t & 63;
#pragma unroll
  for (int i = 0; i < 16; ++i) {
    int kk = tr + i * 4;
    tile[kk][tc] = emb[(size_t)(bk * 64 + kk) * 256 + bd * 64 + tc];
  }
  __syncthreads();
#pragma unroll
  for (int i = 0; i < 16; ++i) {
    int dd = tr + i * 4;
    wT64[(size_t)(bd * 64 + dd) * 1024 + bk * 64 + tc] = (double)tile[tc][dd];
  }
}

// sequential f32 sum of squares per row (mimic XLA:CPU minor-axis reduce)
__global__ __launch_bounds__(256) void k_rowsumsq(const float* __restrict__ a,
                                                  float* __restrict__ outp,
                                                  int rows) {
  int r = blockIdx.x * blockDim.x + threadIdx.x;
  if (r >= rows) return;
  const float* p = a + (size_t)r * DIM;
  float acc = 0.0f;
  for (int i = 0; i < DIM; ++i) {
    float pi = p[i];
    acc = __fadd_rn(acc, __fmul_rn(pi, pi));
  }
  outp[r] = acc;
}

// ----------------------- split path: GEMM then sampler -----------------------

// 32 rows/block, all 1024 cols: f64 MFMA logits -> global buffer (local rows)
__global__ __launch_bounds__(256) void k_logits(const float* __restrict__ x,
                                                const float* __restrict__ wT,
                                                const float* __restrict__ wsum,
                                                const float* __restrict__ xsum,
                                                float* __restrict__ logits,
                                                int chunkbase) {
  __shared__ float xl[32 * 260];
  __shared__ float xs[32];
  int nb = blockIdx.x;
  int t = threadIdx.x;
  int lane = t & 63, wv = t >> 6;
  int m = lane & 15, g = lane >> 4;
  int rg = wv >> 1, chf = wv & 1;   // row-half, col-half

  // stage 32 x-rows (coalesced)
#pragma unroll
  for (int i = 0; i < 32; ++i)
    xl[i * 260 + t] = x[((size_t)(chunkbase + nb * 32) + i) * 256 + t];
  if (t < 32) xs[t] = xsum[chunkbase + nb * 32 + t];
  __syncthreads();

  const float* ap = xl + (rg * 16 + m) * 260 + g;
  for (int ch = 0; ch < 4; ++ch) {
    for (int ct = 0; ct < 8; ++ct) {
      int klocal = chf * 128 + ct * 16 + m;
      int kglob = ch * 256 + klocal;
      f64x4 C = {0.0, 0.0, 0.0, 0.0};
      const float* bp = wT + (size_t)g * 1024 + kglob;   // d = 4*step + g
#pragma unroll 8
      for (int step = 0; step < 64; ++step) {
        double a = (double)ap[step * 4];
        double b = (double)bp[(size_t)step * 4096];
        C = __builtin_amdgcn_mfma_f64_16x16x4f64(a, b, C, 0, 0, 0);
      }
      float ws_k = wsum[kglob];
#pragma unroll
      for (int j = 0; j < 4; ++j) {
        int rloc = rg * 16 + g * 4 + j;
        float l32 = __fsub_rn(__fmul_rn(2.0f, (float)C[j]),
                              __fadd_rn(ws_k, xs[rloc]));
        logits[(size_t)(nb * 32 + rloc) * 1024 + kglob] = l32;
      }
    }
  }
}

// pure sampler: thread = (row, s, k-eighth p). 128 candidates each, k = 4p+32j+e
// winner/runner approx screening + exact f64 resolution, octet shfl reduce.
__global__ __launch_bounds__(256) void k_sampler(const float* __restrict__ logits,
                                                 int* __restrict__ samples,
                                                 int* __restrict__ cnt,
                                                 int chunkbase) {
  int t = threadIdx.x;
  int p = t & 7;
  int rloc = blockIdx.x * 32 + (t >> 3);
  int s = blockIdx.y;
  int row = chunkbase + rloc;
  uint32_t srow = ((uint32_t)s * (uint32_t)NV + (uint32_t)row) * 1024u;

  const float4* lp = (const float4*)(logits + (size_t)rloc * 1024) + p;

  float wvt = -INFINITY, wlv = 0.f, rlv = 0.f;
  int wk = 0, rk = 0, rflag = 0;
  uint32_t wbits = 0u, rbits = 0u;

  for (int j = 0; j < 32; ++j) {
    float4 f = lp[(size_t)j * 8];
    float lvs[4] = {f.x, f.y, f.z, f.w};
    int kb = 4 * p + 32 * j;
#pragma unroll
    for (int e = 0; e < 4; ++e) {
      int k = kb + e;
      uint32_t o0, o1;
      threefry2x32(0u, srow + (uint32_t)k, o0, o1);
      uint32_t bits = o0 ^ o1;
      float vt = __fadd_rn(gumbel_approx(bits), lvs[e]);
      if (vt > wvt) {
        if (wvt > vt - E2G) {       // old winner still in contention
          rk = wk; rbits = wbits; rlv = wlv; rflag = 1;
        }
        wvt = vt; wk = k; wbits = bits; wlv = lvs[e];
      } else if (vt > wvt - E2G) {  // near-tie below winner
        rk = k; rbits = bits; rlv = lvs[e]; rflag = 1;
      }
    }
  }

  // exact resolution of winner (+ rare runner)
  float ev = __fadd_rn(gumbel_exact(wbits), wlv);
  int ek = wk;
  if (rflag) {
    float er = __fadd_rn(gumbel_exact(rbits), rlv);
    if (er > ev || (er == ev && rk < ek)) { ev = er; ek = rk; }
  }
  // octet reduce (lanes p=0..7 share one (row,s)): v desc, k asc
#pragma unroll
  for (int off = 1; off < 8; off <<= 1) {
    float v2 = __shfl_xor(ev, off, 64);
    int   k2 = __shfl_xor(ek, off, 64);
    if (v2 > ev || (v2 == ev && k2 < ek)) { ev = v2; ek = k2; }
  }
  if (p == 0) {
    samples[s * NV + row] = ek;
    atomicAdd(&cnt[ek], 1);
  }
}

// --------------------- fused fallback (R4, validated) ------------------------
__global__ __launch_bounds__(256) void k_fused(const float* __restrict__ x,
                                               const double* __restrict__ wT64,
                                               const float* __restrict__ wsum,
                                               const float* __restrict__ xsum,
                                               int* __restrict__ samples,
                                               int* __restrict__ cnt) {
  __shared__ float xl[16 * 260];
  __shared__ float ll[256 * 17];
  __shared__ float xs[16];
  __shared__ float vred[4 * 16 * 5];
  __shared__ int   kred[4 * 16 * 5];

  int nb = blockIdx.x;
  int t = threadIdx.x;
  int lane = t & 63, wv = t >> 6;
  int m = lane & 15, g = lane >> 4;
  int r = t & 15, kg = t >> 4;

#pragma unroll
  for (int i = 0; i < 16; ++i)
    xl[i * 260 + t] = x[((size_t)nb * 16 + i) * 256 + t];
  if (t < 16) xs[t] = xsum[nb * 16 + t];
  __syncthreads();

  float    wvt[NSAMP], wlv[NSAMP], rlv[NSAMP];
  int      wk[NSAMP], rk[NSAMP];
  uint32_t wbits[NSAMP], rbits[NSAMP];
  uint32_t rvmask = 0;
#pragma unroll
  for (int s = 0; s < NSAMP; ++s) {
    wvt[s] = -INFINITY; wlv[s] = 0.f; wk[s] = 0; wbits[s] = 0u;
    rlv[s] = 0.f; rk[s] = 0; rbits[s] = 0u;
  }
  uint32_t rowbase = ((uint32_t)nb * 16u + (uint32_t)r) * 1024u;

  for (int ch = 0; ch < 4; ++ch) {
    for (int ct = 0; ct < 4; ++ct) {
      int klocal = wv * 64 + ct * 16 + m;
      int kglob = ch * 256 + klocal;
      f64x4 C = {0.0, 0.0, 0.0, 0.0};
      const double* bp = wT64 + (size_t)g * 1024 + kglob;
      const float* ap = xl + m * 260 + g;
#pragma unroll 8
      for (int step = 0; step < 64; ++step) {
        double a = (double)ap[step * 4];
        double b = bp[(size_t)step * 4096];
        C = __builtin_amdgcn_mfma_f64_16x16x4f64(a, b, C, 0, 0, 0);
      }
      float ws_k = wsum[kglob];
#pragma unroll
      for (int j = 0; j < 4; ++j) {
        int row = g * 4 + j;
        float l32 = __fsub_rn(__fmul_rn(2.0f, (float)C[j]),
                              __fadd_rn(ws_k, xs[row]));
        ll[klocal * 17 + row] = l32;
      }
    }
    __syncthreads();
#pragma unroll 1
    for (int i = 0; i < 16; ++i) {
      int kl = kg + (i << 4);
      float lv = ll[kl * 17 + r];
      int gki = (ch << 8) + kl;
      uint32_t cbase = rowbase + (uint32_t)gki;
#pragma unroll
      for (int s = 0; s < NSAMP; ++s) {
        uint32_t o0, o1;
        threefry2x32(0u, cbase + (uint32_t)s * 33554432u, o0, o1);
        uint32_t bits = o0 ^ o1;
        float vt = __fadd_rn(gumbel_approx(bits), lv);
        if (vt > wvt[s]) {
          if (wvt[s] > vt - E2G) {
            rk[s] = wk[s]; rbits[s] = wbits[s]; rlv[s] = wlv[s];
            rvmask |= (1u << s);
          }
          wvt[s] = vt; wk[s] = gki; wbits[s] = bits; wlv[s] = lv;
        } else if (vt > wvt[s] - E2G) {
          rk[s] = gki; rbits[s] = bits; rlv[s] = lv;
          rvmask |= (1u << s);
        }
      }
    }
    __syncthreads();
  }

#pragma unroll
  for (int s = 0; s < NSAMP; ++s) {
    float ev = __fadd_rn(gumbel_exact(wbits[s]), wlv[s]);
    int ek = wk[s];
    if (rvmask & (1u << s)) {
      float er = __fadd_rn(gumbel_exact(rbits[s]), rlv[s]);
      if (er > ev || (er == ev && rk[s] < ek)) { ev = er; ek = rk[s]; }
    }
#pragma unroll
    for (int off = 16; off <= 32; off <<= 1) {
      float v2 = __shfl_xor(ev, off, 64);
      int   k2 = __shfl_xor(ek, off, 64);
      if (v2 > ev || (v2 == ev && k2 < ek)) { ev = v2; ek = k2; }
    }
    if (g == 0) {
      vred[(wv * 16 + r) * 5 + s] = ev;
      kred[(wv * 16 + r) * 5 + s] = ek;
    }
  }
  __syncthreads();
  if (t < 80) {
    int rr = t / 5, s = t % 5;
    float best = vred[rr * 5 + s];
    int bk2 = kred[rr * 5 + s];
#pragma unroll
    for (int w = 1; w < 4; ++w) {
      float v2 = vred[(w * 16 + rr) * 5 + s];
      int   k2 = kred[(w * 16 + rr) * 5 + s];
      if (v2 > best || (v2 == best && k2 < bk2)) { best = v2; bk2 = k2; }
    }
    int n = nb * 16 + rr;
    samples[s * NV + n] = bk2;
    atomicAdd(&cnt[bk2], 1);
  }
}

// ------------------------------ tail kernels ---------------------------------

// merged: exclusive scan (offs/cursor) + normalized counts + perplexity
__global__ __launch_bounds__(1024) void k_meta(const float* __restrict__ ema_count,
                                               const int* __restrict__ cnt,
                                               int* __restrict__ offs,
                                               int* __restrict__ cursor,
                                               double* __restrict__ ncn64,
                                               float* __restrict__ out_count,
                                               float* __restrict__ out_perp) {
  __shared__ int sc[1024];
  __shared__ double red[1024];
  int k = threadIdx.x;
  int v = cnt[k];
  sc[k] = v;
  __syncthreads();
  for (int off = 1; off < 1024; off <<= 1) {
    int a = (k >= off) ? sc[k - off] : 0;
    __syncthreads();
    sc[k] += a;
    __syncthreads();
  }
  int excl = sc[k] - v;
  offs[k] = excl;
  cursor[k] = excl;

  double ec = (double)v * 0.2;
  double nc0 = 0.999 * (double)ema_count[k] + 0.001 * ec;
  red[k] = nc0;
  __syncthreads();
  for (int off = 512; off > 0; off >>= 1) {
    if (k < off) red[k] += red[k + off];
    __syncthreads();
  }
  double ntot = red[0];
  __syncthreads();
  double ncn = (nc0 + 1e-5) / (ntot + (double)KCB * 1e-5) * ntot;
  ncn64[k] = ncn;
  out_count[k] = (float)ncn;

  double avg = ec / (double)NV;
  red[k] = avg * log(avg + 1e-10);
  __syncthreads();
  for (int off = 512; off > 0; off >>= 1) {
    if (k < off) red[k] += red[k + off];
    __syncthreads();
  }
  if (k == 0) out_perp[0] = (float)exp(-red[0]);
}

// scatter sample indices into per-k inverted lists
__global__ __launch_bounds__(256) void k_fill(const int* __restrict__ samples,
                                              int* __restrict__ cursor,
                                              uint32_t* __restrict__ list) {
  int idx = blockIdx.x * 256 + threadIdx.x;   // < 163840
  int k = samples[idx];
  int n = idx & (NV - 1);
  int pos = atomicAdd(&cursor[k], 1);
  list[pos] = (uint32_t)n;
}

// per-k gather of selected x rows -> dw, new_weight, new_embedding
__global__ __launch_bounds__(256) void k_weight2(const float* __restrict__ x,
                                                 const float* __restrict__ ema_w,
                                                 const uint32_t* __restrict__ list,
                                                 const int* __restrict__ offs,
                                                 const int* __restrict__ cnt,
                                                 const double* __restrict__ ncn64,
                                                 float* __restrict__ out_w,
                                                 float* __restrict__ out_emb,
                                                 float* __restrict__ emb32) {
  int k = blockIdx.x, d = threadIdx.x;
  const uint32_t* lp = list + offs[k];
  int mcnt = cnt[k];
  double acc0 = 0.0, acc1 = 0.0;
  int i = 0;
  for (; i + 2 <= mcnt; i += 2) {
    uint32_t n0 = lp[i], n1 = lp[i + 1];
    acc0 += (double)x[(size_t)n0 * 256 + d];
    acc1 += (double)x[(size_t)n1 * 256 + d];
  }
  if (i < mcnt) acc0 += (double)x[(size_t)lp[i] * 256 + d];
  double dw = 0.2 * (acc0 + acc1);
  double nw = 0.999 * (double)ema_w[(size_t)k * 256 + d] + 0.001 * dw;
  float nw32 = (float)nw;
  float e = __fdiv_rn(nw32, (float)ncn64[k]);
  size_t i2 = (size_t)k * 256 + d;
  out_w[i2] = nw32;
  out_emb[i2] = e;
  emb32[i2] = e;
}

// quantized_st + latent loss: 16 rows per block, one f64 atomic per block
__global__ __launch_bounds__(256) void k_quant(const float* __restrict__ x,
                                               const int* __restrict__ samples,
                                               const float* __restrict__ emb32,
                                               float* __restrict__ out_q,
                                               double* __restrict__ lossacc) {
  __shared__ int s5[16][5];
  __shared__ double wred[4];
  int bid = blockIdx.x;
  int t = threadIdx.x;
  if (t < 80) {
    int rr = t / 5, s = t % 5;
    s5[rr][s] = samples[s * NV + bid * 16 + rr];
  }
  __syncthreads();
  double lacc = 0.0;
#pragma unroll 1
  for (int rr = 0; rr < 16; ++rr) {
    size_t n = (size_t)bid * 16 + rr;
    float xv = x[n * DIM + t];
    float acc = emb32[(size_t)s5[rr][0] * DIM + t];
#pragma unroll
    for (int s = 1; s < NSAMP; ++s)
      acc = __fadd_rn(acc, emb32[(size_t)s5[rr][s] * DIM + t]);
    float q = __fdiv_rn(acc, 5.0f);
    out_q[n * DIM + t] = __fadd_rn(xv, __fsub_rn(q, xv));
    float df = __fsub_rn(xv, q);
    lacc += (double)df * (double)df;
  }
  for (int off = 32; off > 0; off >>= 1) lacc += __shfl_down(lacc, off, 64);
  int wid = t >> 6, lane = t & 63;
  if (lane == 0) wred[wid] = lacc;
  __syncthreads();
  if (t == 0) {
    double b = wred[0] + wred[1] + wred[2] + wred[3];
    __hip_atomic_fetch_add(lossacc, b, __ATOMIC_RELAXED, __HIP_MEMORY_SCOPE_AGENT);
  }
}

__global__ void k_loss(const double* __restrict__ lossacc,
                       float* __restrict__ out_loss) {
  out_loss[0] = (float)(0.25 * (lossacc[0] / (double)(NV * DIM)));
}

// ------------------------------- launcher ------------------------------------
extern "C" void kernel_launch(void* const* d_in, const int* in_sizes, int n_in,
                              void* d_out, int out_size, void* d_ws, size_t ws_size,
                              hipStream_t stream) {
  const float* x     = (const float*)d_in[0];   // [64,512,256]
  const float* emb   = (const float*)d_in[1];   // [1024,256]
  const float* ema_c = (const float*)d_in[2];   // [1024]
  const float* ema_w = (const float*)d_in[3];   // [1024,256]

  float* out      = (float*)d_out;
  float* out_q    = out;                 // 8,388,608
  float* out_loss = out + 8388608;       // 1
  float* out_perp = out + 8388609;       // 1
  float* out_emb  = out + 8388610;       // 262,144
  float* out_cnt  = out + 8650754;       // 1,024
  float* out_w    = out + 8651778;       // 262,144

  char* ws = (char*)d_ws;

  // split-path fixed layout
  float*    wT      = (float*)(ws + 0);           // 1,048,576
  float*    wsum    = (float*)(ws + 1048576);     // 4,096
  float*    xsum    = (float*)(ws + 1052672);     // 131,072
  int*      samples = (int*)(ws + 1183744);       // 655,360
  int*      cnt     = (int*)(ws + 1839104);       // 4,096  [zeroed]
  double*   lossacc = (double*)(ws + 1843200);    // 8      [zeroed]
  double*   ncn64   = (double*)(ws + 1843456);    // 8,192
  int*      offs    = (int*)(ws + 1851648);       // 4,096
  int*      cursor  = (int*)(ws + 1855744);       // 4,096
  uint32_t* list    = (uint32_t*)(ws + 1859840);  // 655,360
  float*    emb32   = (float*)(ws + 2515200);     // 1,048,576
  float*    logits  = (float*)(ws + 3563776);     // rest

  size_t avail = (ws_size > 3563776) ? (ws_size - 3563776) : 0;
  size_t maxr = (avail / 4096) & ~(size_t)31;
  int chunk_rows = (maxr > (size_t)NV) ? NV : (int)maxr;
  bool split = (chunk_rows >= 8192);

  if (split) {
    hipMemsetAsync(ws + 1839104, 0, 4096 + 8, stream);
    k_prep32<<<dim3(16, 4), 256, 0, stream>>>(emb, wT);
    k_rowsumsq<<<KCB / 256, 256, 0, stream>>>(emb, wsum, KCB);
    k_rowsumsq<<<NV / 256, 256, 0, stream>>>(x, xsum, NV);
    for (int base = 0; base < NV; base += chunk_rows) {
      int rows = (NV - base < chunk_rows) ? (NV - base) : chunk_rows;
      k_logits<<<rows / 32, 256, 0, stream>>>(x, wT, wsum, xsum, logits, base);
      k_sampler<<<dim3(rows / 32, 5), 256, 0, stream>>>(logits, samples, cnt, base);
    }
    k_meta<<<1, 1024, 0, stream>>>(ema_c, cnt, offs, cursor, ncn64,
                                   out_cnt, out_perp);
    k_fill<<<NV * NSAMP / 256, 256, 0, stream>>>(samples, cursor, list);
    k_weight2<<<KCB, 256, 0, stream>>>(x, ema_w, list, offs, cnt, ncn64,
                                       out_w, out_emb, emb32);
    k_quant<<<NV / 16, 256, 0, stream>>>(x, samples, emb32, out_q, lossacc);
    k_loss<<<1, 1, 0, stream>>>(lossacc, out_loss);
  } else {
    // fused fallback (R4 layout/path, validated)
    double*   wT64_f    = (double*)(ws + 0);          // 2,097,152
    float*    wsum_f    = (float*)(ws + 2097152);
    float*    xsum_f    = (float*)(ws + 2101248);
    int*      samples_f = (int*)(ws + 2232320);
    int*      cnt_f     = (int*)(ws + 2887680);       // [zeroed]
    double*   lossacc_f = (double*)(ws + 2891776);    // [zeroed]
    double*   ncn64_f   = (double*)(ws + 2891784);
    int*      offs_f    = (int*)(ws + 2899976);
    int*      cursor_f  = (int*)(ws + 2904072);
    uint32_t* list_f    = (uint32_t*)(ws + 2908168);
    float*    emb32_f   = (float*)(ws + 3563528);

    hipMemsetAsync(ws + 2887680, 0, 4096 + 8, stream);
    k_prep64<<<dim3(16, 4), 256, 0, stream>>>(emb, wT64_f);
    k_rowsumsq<<<KCB / 256, 256, 0, stream>>>(emb, wsum_f, KCB);
    k_rowsumsq<<<NV / 256, 256, 0, stream>>>(x, xsum_f, NV);
    k_fused<<<NV / 16, 256, 0, stream>>>(x, wT64_f, wsum_f, xsum_f,
                                         samples_f, cnt_f);
    k_meta<<<1, 1024, 0, stream>>>(ema_c, cnt_f, offs_f, cursor_f, ncn64_f,
                                   out_cnt, out_perp);
    k_fill<<<NV * NSAMP / 256, 256, 0, stream>>>(samples_f, cursor_f, list_f);
    k_weight2<<<KCB, 256, 0, stream>>>(x, ema_w, list_f, offs_f, cnt_f, ncn64_f,
                                       out_w, out_emb, emb32_f);
    k_quant<<<NV / 16, 256, 0, stream>>>(x, samples_f, emb32_f, out_q, lossacc_f);
    k_loss<<<1, 1, 0, stream>>>(lossacc_f, out_loss);
  }
}

// Round 6
// 862.325 us; speedup vs baseline: 3.1230x; 1.0726x over previous
//
#include <hip/hip_runtime.h>
#include <stdint.h>
#include <math.h>

#define NV 32768      // N = B*T
#define DIM 256       // D
#define KCB 1024      // K
#define NSAMP 5       // S

typedef double f64x4 __attribute__((ext_vector_type(4)));

// ---------------- threefry2x32 (20 rounds), JAX key = (0, 42) ----------------
__device__ __forceinline__ uint32_t rotl32(uint32_t v, int r) {
  return (v << r) | (v >> (32 - r));
}

__device__ __forceinline__ void threefry2x32(uint32_t c0, uint32_t c1,
                                             uint32_t& o0, uint32_t& o1) {
  const uint32_t k0 = 0u, k1 = 42u;
  const uint32_t k2 = k0 ^ k1 ^ 0x1BD11BDAu;
  uint32_t x0 = c0 + k0, x1 = c1 + k1;
  x0 += x1; x1 = rotl32(x1, 13); x1 ^= x0;
  x0 += x1; x1 = rotl32(x1, 15); x1 ^= x0;
  x0 += x1; x1 = rotl32(x1, 26); x1 ^= x0;
  x0 += x1; x1 = rotl32(x1,  6); x1 ^= x0;
  x0 += k1; x1 += k2 + 1u;
  x0 += x1; x1 = rotl32(x1, 17); x1 ^= x0;
  x0 += x1; x1 = rotl32(x1, 29); x1 ^= x0;
  x0 += x1; x1 = rotl32(x1, 16); x1 ^= x0;
  x0 += x1; x1 = rotl32(x1, 24); x1 ^= x0;
  x0 += k2; x1 += k0 + 2u;
  x0 += x1; x1 = rotl32(x1, 13); x1 ^= x0;
  x0 += x1; x1 = rotl32(x1, 15); x1 ^= x0;
  x0 += x1; x1 = rotl32(x1, 26); x1 ^= x0;
  x0 += x1; x1 = rotl32(x1,  6); x1 ^= x0;
  x0 += k0; x1 += k1 + 3u;
  x0 += x1; x1 = rotl32(x1, 17); x1 ^= x0;
  x0 += x1; x1 = rotl32(x1, 29); x1 ^= x0;
  x0 += x1; x1 = rotl32(x1, 16); x1 ^= x0;
  x0 += x1; x1 = rotl32(x1, 24); x1 ^= x0;
  x0 += k1; x1 += k2 + 4u;
  x0 += x1; x1 = rotl32(x1, 13); x1 ^= x0;
  x0 += x1; x1 = rotl32(x1, 15); x1 ^= x0;
  x0 += x1; x1 = rotl32(x1, 26); x1 ^= x0;
  x0 += x1; x1 = rotl32(x1,  6); x1 ^= x0;
  x0 += k2; x1 += k0 + 5u;
  o0 = x0; o1 = x1;
}

// exact path: f32(-log(x)) via f64 log (rel err < 2^-44) — bit-compatible with
// the correctly-rounded reference logf (validated R1-R5).
__device__ __forceinline__ float neg_log_f32(float xf) {
  uint32_t i = __float_as_uint(xf);
  int e = ((int)(i - 0x3f3504f3u)) >> 23;
  double m = (double)__uint_as_float(i - (uint32_t)(e << 23));
  double z = (m - 1.0) / (m + 1.0);
  double p = z * z;
  double poly = 0x1.1111111111111p-4;          // 1/15
  poly = fma(poly, p, 0x1.3b13b13b13b14p-4);   // 1/13
  poly = fma(poly, p, 0x1.745d1745d1746p-4);   // 1/11
  poly = fma(poly, p, 0x1.c71c71c71c71cp-4);   // 1/9
  poly = fma(poly, p, 0x1.2492492492492p-3);   // 1/7
  poly = fma(poly, p, 0x1.999999999999ap-3);   // 1/5
  poly = fma(poly, p, 0x1.5555555555555p-2);   // 1/3
  poly = fma(poly, p, 1.0);
  double r = fma(-2.0 * z, poly, (double)(-e) * 0x1.62e42fefa39efp-1);
  return (float)r;
}

__device__ __forceinline__ float u_from_bits(uint32_t bits) {
  uint32_t m = bits >> 9;
  return (m == 0u) ? 1.17549435e-38f
                   : (__uint_as_float(m | 0x3f800000u) - 1.0f);
}

__device__ __forceinline__ float gumbel_exact(uint32_t bits) {
  float u = u_from_bits(bits);
  float t = neg_log_f32(u);
  return neg_log_f32(t);
}

// screening approximation: |g_approx - g_exact| <= ~1.5e-6 (v_log_f32 is 1-ulp)
__device__ __forceinline__ float gumbel_approx(uint32_t bits) {
  float u = u_from_bits(bits);
  float t = __log2f(u) * (-0.6931471805599453f);   // ~ -log(u), > 0
  return __log2f(t) * (-0.6931471805599453f);      // ~ -log(t)
}

#define E2G 4e-5f   // near-tie window (>> 2x approx error, ~13x margin)

// ------------------------------- prep kernels --------------------------------

// f32 transpose: wT[d*1024 + k] = emb[k*256 + d], tiled via LDS
__global__ __launch_bounds__(256) void k_prep32(const float* __restrict__ emb,
                                                float* __restrict__ wT) {
  __shared__ float tile[64][65];
  int bk = blockIdx.x;        // k-tile 0..15
  int bd = blockIdx.y;        // d-tile 0..3
  int t = threadIdx.x;
  int tr = t >> 6, tc = t & 63;
#pragma unroll
  for (int i = 0; i < 16; ++i) {
    int kk = tr + i * 4;
    tile[kk][tc] = emb[(size_t)(bk * 64 + kk) * 256 + bd * 64 + tc];
  }
  __syncthreads();
#pragma unroll
  for (int i = 0; i < 16; ++i) {
    int dd = tr + i * 4;
    wT[(size_t)(bd * 64 + dd) * 1024 + bk * 64 + tc] = tile[tc][dd];
  }
}

// f64 transpose (fused-fallback path)
__global__ __launch_bounds__(256) void k_prep64(const float* __restrict__ emb,
                                                double* __restrict__ wT64) {
  __shared__ float tile[64][65];
  int bk = blockIdx.x;
  int bd = blockIdx.y;
  int t = threadIdx.x;
  int tr = t >> 6, tc = t & 63;
#pragma unroll
  for (int i = 0; i < 16; ++i) {
    int kk = tr + i * 4;
    tile[kk][tc] = emb[(size_t)(bk * 64 + kk) * 256 + bd * 64 + tc];
  }
  __syncthreads();
#pragma unroll
  for (int i = 0; i < 16; ++i) {
    int dd = tr + i * 4;
    wT64[(size_t)(bd * 64 + dd) * 1024 + bk * 64 + tc] = (double)tile[tc][dd];
  }
}

// sequential f32 sum of squares per row (mimic XLA:CPU minor-axis reduce)
__global__ __launch_bounds__(256) void k_rowsumsq(const float* __restrict__ a,
                                                  float* __restrict__ outp,
                                                  int rows) {
  int r = blockIdx.x * blockDim.x + threadIdx.x;
  if (r >= rows) return;
  const float* p = a + (size_t)r * DIM;
  float acc = 0.0f;
  for (int i = 0; i < DIM; ++i) {
    float pi = p[i];
    acc = __fadd_rn(acc, __fmul_rn(pi, pi));
  }
  outp[r] = acc;
}

// ----------------------- split path: GEMM then sampler -----------------------

// 32 rows/block, all 1024 cols: f64 MFMA logits -> global buffer (local rows).
// xsum computed in-kernel from the staged LDS tile (bit-exact sequential f32).
__global__ __launch_bounds__(256) void k_logits(const float* __restrict__ x,
                                                const float* __restrict__ wT,
                                                const float* __restrict__ wsum,
                                                float* __restrict__ logits,
                                                int chunkbase) {
  __shared__ float xl[32 * 260];
  __shared__ float xs[32];
  int nb = blockIdx.x;
  int t = threadIdx.x;
  int lane = t & 63, wv = t >> 6;
  int m = lane & 15, g = lane >> 4;
  int rg = wv >> 1, chf = wv & 1;   // row-half, col-half

  // stage 32 x-rows (coalesced)
#pragma unroll
  for (int i = 0; i < 32; ++i)
    xl[i * 260 + t] = x[((size_t)(chunkbase + nb * 32) + i) * 256 + t];
  __syncthreads();

  // in-kernel xsum: sequential f32 per row (1 thread per row, exact order)
  if (t < 32) {
    const float* p = xl + t * 260;
    float acc = 0.0f;
    for (int i = 0; i < DIM; ++i) {
      float pi = p[i];
      acc = __fadd_rn(acc, __fmul_rn(pi, pi));
    }
    xs[t] = acc;
  }
  __syncthreads();

  const float* ap = xl + (rg * 16 + m) * 260 + g;
  for (int ch = 0; ch < 4; ++ch) {
    for (int ct = 0; ct < 8; ++ct) {
      int klocal = chf * 128 + ct * 16 + m;
      int kglob = ch * 256 + klocal;
      f64x4 C = {0.0, 0.0, 0.0, 0.0};
      const float* bp = wT + (size_t)g * 1024 + kglob;   // d = 4*step + g
#pragma unroll 8
      for (int step = 0; step < 64; ++step) {
        double a = (double)ap[step * 4];
        double b = (double)bp[(size_t)step * 4096];
        C = __builtin_amdgcn_mfma_f64_16x16x4f64(a, b, C, 0, 0, 0);
      }
      float ws_k = wsum[kglob];
#pragma unroll
      for (int j = 0; j < 4; ++j) {
        int rloc = rg * 16 + g * 4 + j;
        float l32 = __fsub_rn(__fmul_rn(2.0f, (float)C[j]),
                              __fadd_rn(ws_k, xs[rloc]));
        logits[(size_t)(nb * 32 + rloc) * 1024 + kglob] = l32;
      }
    }
  }
}

// pure sampler v2: thread = (row, k-eighth p) handling ALL 5 samples.
// Logits read once; 20 unrolled (e x s) bodies; branchless winner update;
// rare exec-masked runner branch; exact f64 resolution of winner/runner.
__global__ __launch_bounds__(256) void k_sampler(const float* __restrict__ logits,
                                                 int* __restrict__ samples,
                                                 int* __restrict__ cnt,
                                                 int chunkbase) {
  int t = threadIdx.x;
  int p = t & 7;
  int rloc = blockIdx.x * 32 + (t >> 3);
  int row = chunkbase + rloc;
  uint32_t rowk = (uint32_t)row * 1024u;

  const float4* lp = (const float4*)(logits + (size_t)rloc * 1024) + p;

  float    wvt[NSAMP], wlv[NSAMP], rlv[NSAMP];
  int      wk[NSAMP], rk[NSAMP];
  uint32_t wbits[NSAMP], rbits[NSAMP];
  uint32_t rmask = 0;
#pragma unroll
  for (int s = 0; s < NSAMP; ++s) {
    wvt[s] = -INFINITY; wlv[s] = 0.f; wk[s] = 0; wbits[s] = 0u;
    rlv[s] = 0.f; rk[s] = 0; rbits[s] = 0u;
  }

#pragma unroll 1
  for (int j = 0; j < 32; ++j) {
    float4 f = lp[(size_t)j * 8];
    float lvs[4] = {f.x, f.y, f.z, f.w};
    int kb = 4 * p + 32 * j;
#pragma unroll
    for (int e = 0; e < 4; ++e) {
      int k = kb + e;
      float lv = lvs[e];
      uint32_t cbase = rowk + (uint32_t)k;
#pragma unroll
      for (int s = 0; s < NSAMP; ++s) {
        uint32_t o0, o1;
        threefry2x32(0u, cbase + (uint32_t)s * 33554432u, o0, o1);
        uint32_t bits = o0 ^ o1;
        float vt = __fadd_rn(gumbel_approx(bits), lv);
        float wpre = wvt[s];
        // rare near-tie event: |vt - wpre| < E2G  (either direction)
        if (fminf(vt, wpre) > fmaxf(vt, wpre) - E2G) {
          if (vt > wpre) { rk[s] = wk[s]; rbits[s] = wbits[s]; rlv[s] = wlv[s]; }
          else           { rk[s] = k;     rbits[s] = bits;     rlv[s] = lv; }
          rmask |= (1u << s);
        }
        // branchless winner update (strict >, k ascending per thread)
        bool gt = vt > wpre;
        wvt[s]   = gt ? vt   : wpre;
        wk[s]    = gt ? k    : wk[s];
        wbits[s] = gt ? bits : wbits[s];
        wlv[s]   = gt ? lv   : wlv[s];
      }
    }
  }

  // exact resolution + octet reduce (lanes p=0..7 share one row): v desc, k asc
#pragma unroll
  for (int s = 0; s < NSAMP; ++s) {
    float ev = __fadd_rn(gumbel_exact(wbits[s]), wlv[s]);
    int ek = wk[s];
    if (rmask & (1u << s)) {
      float er = __fadd_rn(gumbel_exact(rbits[s]), rlv[s]);
      if (er > ev || (er == ev && rk[s] < ek)) { ev = er; ek = rk[s]; }
    }
#pragma unroll
    for (int off = 1; off < 8; off <<= 1) {
      float v2 = __shfl_xor(ev, off, 64);
      int   k2 = __shfl_xor(ek, off, 64);
      if (v2 > ev || (v2 == ev && k2 < ek)) { ev = v2; ek = k2; }
    }
    if (p == 0) {
      samples[s * NV + row] = ek;
      atomicAdd(&cnt[ek], 1);
    }
  }
}

// --------------------- fused fallback (R4, validated) ------------------------
__global__ __launch_bounds__(256) void k_fused(const float* __restrict__ x,
                                               const double* __restrict__ wT64,
                                               const float* __restrict__ wsum,
                                               const float* __restrict__ xsum,
                                               int* __restrict__ samples,
                                               int* __restrict__ cnt) {
  __shared__ float xl[16 * 260];
  __shared__ float ll[256 * 17];
  __shared__ float xs[16];
  __shared__ float vred[4 * 16 * 5];
  __shared__ int   kred[4 * 16 * 5];

  int nb = blockIdx.x;
  int t = threadIdx.x;
  int lane = t & 63, wv = t >> 6;
  int m = lane & 15, g = lane >> 4;
  int r = t & 15, kg = t >> 4;

#pragma unroll
  for (int i = 0; i < 16; ++i)
    xl[i * 260 + t] = x[((size_t)nb * 16 + i) * 256 + t];
  if (t < 16) xs[t] = xsum[nb * 16 + t];
  __syncthreads();

  float    wvt[NSAMP], wlv[NSAMP], rlv[NSAMP];
  int      wk[NSAMP], rk[NSAMP];
  uint32_t wbits[NSAMP], rbits[NSAMP];
  uint32_t rvmask = 0;
#pragma unroll
  for (int s = 0; s < NSAMP; ++s) {
    wvt[s] = -INFINITY; wlv[s] = 0.f; wk[s] = 0; wbits[s] = 0u;
    rlv[s] = 0.f; rk[s] = 0; rbits[s] = 0u;
  }
  uint32_t rowbase = ((uint32_t)nb * 16u + (uint32_t)r) * 1024u;

  for (int ch = 0; ch < 4; ++ch) {
    for (int ct = 0; ct < 4; ++ct) {
      int klocal = wv * 64 + ct * 16 + m;
      int kglob = ch * 256 + klocal;
      f64x4 C = {0.0, 0.0, 0.0, 0.0};
      const double* bp = wT64 + (size_t)g * 1024 + kglob;
      const float* ap = xl + m * 260 + g;
#pragma unroll 8
      for (int step = 0; step < 64; ++step) {
        double a = (double)ap[step * 4];
        double b = bp[(size_t)step * 4096];
        C = __builtin_amdgcn_mfma_f64_16x16x4f64(a, b, C, 0, 0, 0);
      }
      float ws_k = wsum[kglob];
#pragma unroll
      for (int j = 0; j < 4; ++j) {
        int row = g * 4 + j;
        float l32 = __fsub_rn(__fmul_rn(2.0f, (float)C[j]),
                              __fadd_rn(ws_k, xs[row]));
        ll[klocal * 17 + row] = l32;
      }
    }
    __syncthreads();
#pragma unroll 1
    for (int i = 0; i < 16; ++i) {
      int kl = kg + (i << 4);
      float lv = ll[kl * 17 + r];
      int gki = (ch << 8) + kl;
      uint32_t cbase = rowbase + (uint32_t)gki;
#pragma unroll
      for (int s = 0; s < NSAMP; ++s) {
        uint32_t o0, o1;
        threefry2x32(0u, cbase + (uint32_t)s * 33554432u, o0, o1);
        uint32_t bits = o0 ^ o1;
        float vt = __fadd_rn(gumbel_approx(bits), lv);
        if (vt > wvt[s]) {
          if (wvt[s] > vt - E2G) {
            rk[s] = wk[s]; rbits[s] = wbits[s]; rlv[s] = wlv[s];
            rvmask |= (1u << s);
          }
          wvt[s] = vt; wk[s] = gki; wbits[s] = bits; wlv[s] = lv;
        } else if (vt > wvt[s] - E2G) {
          rk[s] = gki; rbits[s] = bits; rlv[s] = lv;
          rvmask |= (1u << s);
        }
      }
    }
    __syncthreads();
  }

#pragma unroll
  for (int s = 0; s < NSAMP; ++s) {
    float ev = __fadd_rn(gumbel_exact(wbits[s]), wlv[s]);
    int ek = wk[s];
    if (rvmask & (1u << s)) {
      float er = __fadd_rn(gumbel_exact(rbits[s]), rlv[s]);
      if (er > ev || (er == ev && rk[s] < ek)) { ev = er; ek = rk[s]; }
    }
#pragma unroll
    for (int off = 16; off <= 32; off <<= 1) {
      float v2 = __shfl_xor(ev, off, 64);
      int   k2 = __shfl_xor(ek, off, 64);
      if (v2 > ev || (v2 == ev && k2 < ek)) { ev = v2; ek = k2; }
    }
    if (g == 0) {
      vred[(wv * 16 + r) * 5 + s] = ev;
      kred[(wv * 16 + r) * 5 + s] = ek;
    }
  }
  __syncthreads();
  if (t < 80) {
    int rr = t / 5, s = t % 5;
    float best = vred[rr * 5 + s];
    int bk2 = kred[rr * 5 + s];
#pragma unroll
    for (int w = 1; w < 4; ++w) {
      float v2 = vred[(w * 16 + rr) * 5 + s];
      int   k2 = kred[(w * 16 + rr) * 5 + s];
      if (v2 > best || (v2 == best && k2 < bk2)) { best = v2; bk2 = k2; }
    }
    int n = nb * 16 + rr;
    samples[s * NV + n] = bk2;
    atomicAdd(&cnt[bk2], 1);
  }
}

// ------------------------------ tail kernels ---------------------------------

// merged: exclusive scan (offs/cursor) + normalized counts + perplexity
__global__ __launch_bounds__(1024) void k_meta(const float* __restrict__ ema_count,
                                               const int* __restrict__ cnt,
                                               int* __restrict__ offs,
                                               int* __restrict__ cursor,
                                               double* __restrict__ ncn64,
                                               float* __restrict__ out_count,
                                               float* __restrict__ out_perp) {
  __shared__ int sc[1024];
  __shared__ double red[1024];
  int k = threadIdx.x;
  int v = cnt[k];
  sc[k] = v;
  __syncthreads();
  for (int off = 1; off < 1024; off <<= 1) {
    int a = (k >= off) ? sc[k - off] : 0;
    __syncthreads();
    sc[k] += a;
    __syncthreads();
  }
  int excl = sc[k] - v;
  offs[k] = excl;
  cursor[k] = excl;

  double ec = (double)v * 0.2;
  double nc0 = 0.999 * (double)ema_count[k] + 0.001 * ec;
  red[k] = nc0;
  __syncthreads();
  for (int off = 512; off > 0; off >>= 1) {
    if (k < off) red[k] += red[k + off];
    __syncthreads();
  }
  double ntot = red[0];
  __syncthreads();
  double ncn = (nc0 + 1e-5) / (ntot + (double)KCB * 1e-5) * ntot;
  ncn64[k] = ncn;
  out_count[k] = (float)ncn;

  double avg = ec / (double)NV;
  red[k] = avg * log(avg + 1e-10);
  __syncthreads();
  for (int off = 512; off > 0; off >>= 1) {
    if (k < off) red[k] += red[k + off];
    __syncthreads();
  }
  if (k == 0) out_perp[0] = (float)exp(-red[0]);
}

// scatter sample indices into per-k inverted lists
__global__ __launch_bounds__(256) void k_fill(const int* __restrict__ samples,
                                              int* __restrict__ cursor,
                                              uint32_t* __restrict__ list) {
  int idx = blockIdx.x * 256 + threadIdx.x;   // < 163840
  int k = samples[idx];
  int n = idx & (NV - 1);
  int pos = atomicAdd(&cursor[k], 1);
  list[pos] = (uint32_t)n;
}

// per-k gather of selected x rows -> dw, new_weight, new_embedding
__global__ __launch_bounds__(256) void k_weight2(const float* __restrict__ x,
                                                 const float* __restrict__ ema_w,
                                                 const uint32_t* __restrict__ list,
                                                 const int* __restrict__ offs,
                                                 const int* __restrict__ cnt,
                                                 const double* __restrict__ ncn64,
                                                 float* __restrict__ out_w,
                                                 float* __restrict__ out_emb,
                                                 float* __restrict__ emb32) {
  int k = blockIdx.x, d = threadIdx.x;
  const uint32_t* lp = list + offs[k];
  int mcnt = cnt[k];
  double acc0 = 0.0, acc1 = 0.0;
  int i = 0;
  for (; i + 2 <= mcnt; i += 2) {
    uint32_t n0 = lp[i], n1 = lp[i + 1];
    acc0 += (double)x[(size_t)n0 * 256 + d];
    acc1 += (double)x[(size_t)n1 * 256 + d];
  }
  if (i < mcnt) acc0 += (double)x[(size_t)lp[i] * 256 + d];
  double dw = 0.2 * (acc0 + acc1);
  double nw = 0.999 * (double)ema_w[(size_t)k * 256 + d] + 0.001 * dw;
  float nw32 = (float)nw;
  float e = __fdiv_rn(nw32, (float)ncn64[k]);
  size_t i2 = (size_t)k * 256 + d;
  out_w[i2] = nw32;
  out_emb[i2] = e;
  emb32[i2] = e;
}

// quantized_st + latent loss: 16 rows per block, one f64 atomic per block
__global__ __launch_bounds__(256) void k_quant(const float* __restrict__ x,
                                               const int* __restrict__ samples,
                                               const float* __restrict__ emb32,
                                               float* __restrict__ out_q,
                                               double* __restrict__ lossacc) {
  __shared__ int s5[16][5];
  __shared__ double wred[4];
  int bid = blockIdx.x;
  int t = threadIdx.x;
  if (t < 80) {
    int rr = t / 5, s = t % 5;
    s5[rr][s] = samples[s * NV + bid * 16 + rr];
  }
  __syncthreads();
  double lacc = 0.0;
#pragma unroll 1
  for (int rr = 0; rr < 16; ++rr) {
    size_t n = (size_t)bid * 16 + rr;
    float xv = x[n * DIM + t];
    float acc = emb32[(size_t)s5[rr][0] * DIM + t];
#pragma unroll
    for (int s = 1; s < NSAMP; ++s)
      acc = __fadd_rn(acc, emb32[(size_t)s5[rr][s] * DIM + t]);
    float q = __fdiv_rn(acc, 5.0f);
    out_q[n * DIM + t] = __fadd_rn(xv, __fsub_rn(q, xv));
    float df = __fsub_rn(xv, q);
    lacc += (double)df * (double)df;
  }
  for (int off = 32; off > 0; off >>= 1) lacc += __shfl_down(lacc, off, 64);
  int wid = t >> 6, lane = t & 63;
  if (lane == 0) wred[wid] = lacc;
  __syncthreads();
  if (t == 0) {
    double b = wred[0] + wred[1] + wred[2] + wred[3];
    __hip_atomic_fetch_add(lossacc, b, __ATOMIC_RELAXED, __HIP_MEMORY_SCOPE_AGENT);
  }
}

__global__ void k_loss(const double* __restrict__ lossacc,
                       float* __restrict__ out_loss) {
  out_loss[0] = (float)(0.25 * (lossacc[0] / (double)(NV * DIM)));
}

// ------------------------------- launcher ------------------------------------
extern "C" void kernel_launch(void* const* d_in, const int* in_sizes, int n_in,
                              void* d_out, int out_size, void* d_ws, size_t ws_size,
                              hipStream_t stream) {
  const float* x     = (const float*)d_in[0];   // [64,512,256]
  const float* emb   = (const float*)d_in[1];   // [1024,256]
  const float* ema_c = (const float*)d_in[2];   // [1024]
  const float* ema_w = (const float*)d_in[3];   // [1024,256]

  float* out      = (float*)d_out;
  float* out_q    = out;                 // 8,388,608
  float* out_loss = out + 8388608;       // 1
  float* out_perp = out + 8388609;       // 1
  float* out_emb  = out + 8388610;       // 262,144
  float* out_cnt  = out + 8650754;       // 1,024
  float* out_w    = out + 8651778;       // 262,144

  char* ws = (char*)d_ws;

  // split-path fixed layout
  float*    wT      = (float*)(ws + 0);           // 1,048,576
  float*    wsum    = (float*)(ws + 1048576);     // 4,096
  float*    xsum    = (float*)(ws + 1052672);     // 131,072 (fallback only)
  int*      samples = (int*)(ws + 1183744);       // 655,360
  int*      cnt     = (int*)(ws + 1839104);       // 4,096  [zeroed]
  double*   lossacc = (double*)(ws + 1843200);    // 8      [zeroed]
  double*   ncn64   = (double*)(ws + 1843456);    // 8,192
  int*      offs    = (int*)(ws + 1851648);       // 4,096
  int*      cursor  = (int*)(ws + 1855744);       // 4,096
  uint32_t* list    = (uint32_t*)(ws + 1859840);  // 655,360
  float*    emb32   = (float*)(ws + 2515200);     // 1,048,576
  float*    logits  = (float*)(ws + 3563776);     // rest

  size_t avail = (ws_size > 3563776) ? (ws_size - 3563776) : 0;
  size_t maxr = (avail / 4096) & ~(size_t)31;
  int chunk_rows = (maxr > (size_t)NV) ? NV : (int)maxr;
  bool split = (chunk_rows >= 8192);

  if (split) {
    hipMemsetAsync(ws + 1839104, 0, 4096 + 8, stream);
    k_prep32<<<dim3(16, 4), 256, 0, stream>>>(emb, wT);
    k_rowsumsq<<<KCB / 256, 256, 0, stream>>>(emb, wsum, KCB);
    for (int base = 0; base < NV; base += chunk_rows) {
      int rows = (NV - base < chunk_rows) ? (NV - base) : chunk_rows;
      k_logits<<<rows / 32, 256, 0, stream>>>(x, wT, wsum, logits, base);
      k_sampler<<<rows / 32, 256, 0, stream>>>(logits, samples, cnt, base);
    }
    k_meta<<<1, 1024, 0, stream>>>(ema_c, cnt, offs, cursor, ncn64,
                                   out_cnt, out_perp);
    k_fill<<<NV * NSAMP / 256, 256, 0, stream>>>(samples, cursor, list);
    k_weight2<<<KCB, 256, 0, stream>>>(x, ema_w, list, offs, cnt, ncn64,
                                       out_w, out_emb, emb32);
    k_quant<<<NV / 16, 256, 0, stream>>>(x, samples, emb32, out_q, lossacc);
    k_loss<<<1, 1, 0, stream>>>(lossacc, out_loss);
  } else {
    // fused fallback (R4 layout/path, validated)
    double*   wT64_f    = (double*)(ws + 0);          // 2,097,152
    float*    wsum_f    = (float*)(ws + 2097152);
    float*    xsum_f    = (float*)(ws + 2101248);
    int*      samples_f = (int*)(ws + 2232320);
    int*      cnt_f     = (int*)(ws + 2887680);       // [zeroed]
    double*   lossacc_f = (double*)(ws + 2891776);    // [zeroed]
    double*   ncn64_f   = (double*)(ws + 2891784);
    int*      offs_f    = (int*)(ws + 2899976);
    int*      cursor_f  = (int*)(ws + 2904072);
    uint32_t* list_f    = (uint32_t*)(ws + 2908168);
    float*    emb32_f   = (float*)(ws + 3563528);

    hipMemsetAsync(ws + 2887680, 0, 4096 + 8, stream);
    k_prep64<<<dim3(16, 4), 256, 0, stream>>>(emb, wT64_f);
    k_rowsumsq<<<KCB / 256, 256, 0, stream>>>(emb, wsum_f, KCB);
    k_rowsumsq<<<NV / 256, 256, 0, stream>>>(x, xsum_f, NV);
    k_fused<<<NV / 16, 256, 0, stream>>>(x, wT64_f, wsum_f, xsum_f,
                                         samples_f, cnt_f);
    k_meta<<<1, 1024, 0, stream>>>(ema_c, cnt_f, offs_f, cursor_f, ncn64_f,
                                   out_cnt, out_perp);
    k_fill<<<NV * NSAMP / 256, 256, 0, stream>>>(samples_f, cursor_f, list_f);
    k_weight2<<<KCB, 256, 0, stream>>>(x, ema_w, list_f, offs_f, cnt_f, ncn64_f,
                                       out_w, out_emb, emb32_f);
    k_quant<<<NV / 16, 256, 0, stream>>>(x, samples_f, emb32_f, out_q, lossacc_f);
    k_loss<<<1, 1, 0, stream>>>(lossacc_f, out_loss);
  }
}